// Round 14
// baseline (1586.365 us; speedup 1.0000x reference)
//
#include <hip/hip_runtime.h>
#include <hip/hip_bf16.h>
#include <math.h>

// ---------------------------------------------------------------------------
// Types
// ---------------------------------------------------------------------------
typedef __bf16 bf16_t;
typedef __bf16 bf16x8 __attribute__((ext_vector_type(8)));
typedef __bf16 bf16x4 __attribute__((ext_vector_type(4)));
typedef float  f32x4  __attribute__((ext_vector_type(4)));

#define MFMA_BF16(a, b, c) __builtin_amdgcn_mfma_f32_16x16x32_bf16((a), (b), (c), 0, 0, 0)

typedef const void __attribute__((address_space(1)))* gas_ptr;
typedef void       __attribute__((address_space(3)))* las_ptr;

__device__ __forceinline__ void gload_lds16(const void* g, void* l) {
  // global -> LDS direct, 16B per lane. LDS dest is wave-uniform base + lane*16.
  __builtin_amdgcn_global_load_lds((gas_ptr)g, (las_ptr)l, 16, 0, 0);
}

// ---------------------------------------------------------------------------
// Model constants
// ---------------------------------------------------------------------------
static constexpr int B_ = 4, S_ = 1024, D_ = 1024, HF_ = 4096, V_ = 32000;
static constexpr int NH_ = 16, HD_ = 64;
static constexpr int TOK_ = B_ * S_;  // 4096

// ---------------------------------------------------------------------------
// fp32 -> bf16 conversion (vectorized x4)
// ---------------------------------------------------------------------------
__global__ __launch_bounds__(256) void cvt_f32_bf16(const float* __restrict__ in,
                                                    bf16_t* __restrict__ out, int n4) {
  int i = blockIdx.x * 256 + threadIdx.x;
  if (i < n4) {
    float4 v = ((const float4*)in)[i];
    bf16x4 o;
    o[0] = (bf16_t)v.x; o[1] = (bf16_t)v.y; o[2] = (bf16_t)v.z; o[3] = (bf16_t)v.w;
    ((bf16x4*)out)[i] = o;
  }
}

// ---------------------------------------------------------------------------
// Sinusoidal positional encoding table
// ---------------------------------------------------------------------------
__global__ __launch_bounds__(256) void pe_kernel(float* __restrict__ pe) {
  const int s = blockIdx.x;
  for (int i = threadIdx.x; i < D_ / 2; i += 256) {
    float div = expf((2.0f * (float)i) * (-9.210340371976184f / (float)D_)); // ln(10000)
    float a = (float)s * div;
    pe[(size_t)s * D_ + 2 * i]     = sinf(a);
    pe[(size_t)s * D_ + 2 * i + 1] = cosf(a);
  }
}

// ---------------------------------------------------------------------------
// Embedding: h[t][d] = emb_W[x[t]][d] * 32 + pe[t % S][d]
// ---------------------------------------------------------------------------
__global__ __launch_bounds__(256) void embed_kernel(const int* __restrict__ x,
                                                    const float* __restrict__ embW,
                                                    const float* __restrict__ pe,
                                                    float* __restrict__ h) {
  int i = blockIdx.x * 256 + threadIdx.x;
  int token = i >> 8;
  int c4 = i & 255;
  int idx = x[token];
  float4 e = ((const float4*)(embW + (size_t)idx * D_))[c4];
  float4 p = ((const float4*)(pe + (size_t)(token & (S_ - 1)) * D_))[c4];
  float4 o;
  o.x = e.x * 32.0f + p.x; o.y = e.y * 32.0f + p.y;
  o.z = e.z * 32.0f + p.z; o.w = e.w * 32.0f + p.w;
  ((float4*)(h + (size_t)token * D_))[c4] = o;
}

// ---------------------------------------------------------------------------
// a_in = h + LayerNorm(h)*g + b   -> bf16
// ---------------------------------------------------------------------------
__global__ __launch_bounds__(256) void ln_res_kernel(const float* __restrict__ h,
                                                     const float* __restrict__ gamma,
                                                     const float* __restrict__ beta,
                                                     bf16_t* __restrict__ out) {
  const int row = blockIdx.x;
  const int tid = threadIdx.x;
  const float4 v = ((const float4*)(h + (size_t)row * D_))[tid];
  float s  = v.x + v.y + v.z + v.w;
  float s2 = v.x * v.x + v.y * v.y + v.z * v.z + v.w * v.w;
#pragma unroll
  for (int m = 1; m < 64; m <<= 1) {
    s  += __shfl_xor(s, m, 64);
    s2 += __shfl_xor(s2, m, 64);
  }
  __shared__ float red[2][4];
  const int wave = tid >> 6, lane = tid & 63;
  if (lane == 0) { red[0][wave] = s; red[1][wave] = s2; }
  __syncthreads();
  s  = red[0][0] + red[0][1] + red[0][2] + red[0][3];
  s2 = red[1][0] + red[1][1] + red[1][2] + red[1][3];
  const float mu   = s * (1.0f / D_);
  const float rstd = rsqrtf(s2 * (1.0f / D_) - mu * mu + 1e-5f);
  const float4 g4 = ((const float4*)gamma)[tid];
  const float4 b4 = ((const float4*)beta)[tid];
  bf16x4 o;
  o[0] = (bf16_t)(v.x + (v.x - mu) * rstd * g4.x + b4.x);
  o[1] = (bf16_t)(v.y + (v.y - mu) * rstd * g4.y + b4.y);
  o[2] = (bf16_t)(v.z + (v.z - mu) * rstd * g4.z + b4.z);
  o[3] = (bf16_t)(v.w + (v.w - mu) * rstd * g4.w + b4.w);
  ((bf16x4*)(out + (size_t)row * D_))[tid] = o;
}

// ---------------------------------------------------------------------------
// gemm_sq: 128x128 tile, BK=64, 2 phases/K-tile, 2 blocks/CU (verified r10).
// C[4096,N] = A[4096,K] @ W[N,K]^T. 8 waves (2M x 4N); per-wave 64x32.
// LDS 2 x 32 KB dbuf; launch_bounds(512,4) => 2 blocks/CU; sibling block
// covers barrier/drain/epilogue stalls. Counted vmcnt(2), never 0 mid-loop.
// Swizzle: 128B rows, byte ^ ((row&7)<<4), involution. XCD swizzle +
// 2-D SUPERTILE ordering (verified r13: logits FETCH 1.03GB -> 0.37GB).
// Logits passes (band_n=250, mch=4): the supertile decode then degenerates
// to per-XCD STATIC M-OWNERSHIP - stid = logical/1000 = XCD id, so each XCD
// keeps a 1 MB A-chunk L2-resident forever and sweeps all N; all 8 XCDs
// stream B in the same ascending-N order -> first toucher fills L3, the
// other 7 hit it. Ideal HBM reads ~ A 8MB + B 65MB.
// Per-layer GEMMs pass (band_n=N/128, mch=32) == verified r10 decode.
// Epilogues: 0 QKV-scatter, 1 fout+=v, 2 relu(v+bias)->bf16, 3 fout+=v+bias,
//            4 fout = v + bias (pure store, logits).
// ---------------------------------------------------------------------------
template <int EPI>
__global__ __launch_bounds__(512, 4) void gemm_sq(
    const bf16_t* __restrict__ A, const bf16_t* __restrict__ W, int N, int K,
    int band_n, int mch,
    float* __restrict__ fout, const float* __restrict__ bias, bf16_t* __restrict__ bout,
    bf16_t* __restrict__ qb, bf16_t* __restrict__ kb, bf16_t* __restrict__ vtb) {
  __shared__ char lds[2][32768];

  const int tid = threadIdx.x;
  const int wave = tid >> 6, lane = tid & 63;
  const int row16 = lane & 15, kgrp = lane >> 4;
  const int wm = wave >> 2, wn = wave & 3;  // 2M x 4N

  const int nb = gridDim.x;  // multiple of 8
  const int logical = (blockIdx.x & 7) * (nb >> 3) + (blockIdx.x >> 3);
  // supertile decode: {band of band_n N-tiles} x {chunk of mch M-tiles},
  // M fastest within supertile; chunks inner, bands outer. (M = 32 tiles)
  const int st = band_n * mch;
  const int stid = logical / st;
  const int rr = logical - stid * st;
  const int nMch = 32 / mch;
  const int band = stid / nMch;
  const int mchid = stid - band * nMch;
  const int m0 = (mchid * mch + (rr % mch)) << 7;
  const int n0 = (band * band_n + rr / mch) << 7;
  const size_t K2 = (size_t)K * 2;

  const int lr = lane >> 3;
  const int swz = ((lane & 7) * 16) ^ (lr << 4);
  const char* gA = (const char*)A + (size_t)(m0 + wave * 8 + lr) * K2 + swz;
  const char* gB = (const char*)W + (size_t)(n0 + wave * 8 + lr) * K2 + swz;
  char* const ldsc = &lds[0][0];
  const int dW = wave * 1024;

#define STG_A(v)                                                  \
  { char* d_ = ldsc + (((v) & 1) << 15) + dW;                     \
    const char* g_ = gA + (size_t)(v) * 128;                      \
    gload_lds16(g_, d_); gload_lds16(g_ + 64 * K2, d_ + 8192); }
#define STG_B(v)                                                  \
  { char* d_ = ldsc + (((v) & 1) << 15) + 16384 + dW;             \
    const char* g_ = gB + (size_t)(v) * 128;                      \
    gload_lds16(g_, d_); gload_lds16(g_ + 64 * K2, d_ + 8192); }

  const int colx0 = (kgrp * 16) ^ ((row16 & 7) << 4);
  const int colx1 = (64 + kgrp * 16) ^ ((row16 & 7) << 4);
  int aoff[4], boff[2];
#pragma unroll
  for (int mf = 0; mf < 4; mf++) aoff[mf] = (wm * 64 + mf * 16 + row16) * 128;
#pragma unroll
  for (int nf = 0; nf < 2; nf++) boff[nf] = 16384 + (nf * 64 + wn * 16 + row16) * 128;

#define GATE()                                        \
  __builtin_amdgcn_s_barrier();                       \
  asm volatile("s_waitcnt lgkmcnt(0)" ::: "memory");  \
  __builtin_amdgcn_sched_barrier(0);

  f32x4 acc[4][2] = {};
  bf16x8 af[4][2], bfr[2];
  const int NT = K >> 6;

  STG_A(0); STG_B(0); STG_A(1);
  asm volatile("s_waitcnt vmcnt(2)" ::: "memory");  // A(0), B(0) landed
  __builtin_amdgcn_s_barrier();

  for (int t = 0; t < NT; ++t) {
    const char* bufp = ldsc + ((t & 1) << 15);
    // ---- P0: all m x n01 ----
#pragma unroll
    for (int mf = 0; mf < 4; mf++) {
      af[mf][0] = *(const bf16x8*)(bufp + aoff[mf] + colx0);
      af[mf][1] = *(const bf16x8*)(bufp + aoff[mf] + colx1);
    }
    bfr[0] = *(const bf16x8*)(bufp + boff[0] + colx0);
    bfr[1] = *(const bf16x8*)(bufp + boff[0] + colx1);
    if (t + 1 < NT) STG_B(t + 1);
    GATE();
    __builtin_amdgcn_s_setprio(1);
#pragma unroll
    for (int mf = 0; mf < 4; mf++) {
      acc[mf][0] = MFMA_BF16(af[mf][0], bfr[0], acc[mf][0]);
      acc[mf][0] = MFMA_BF16(af[mf][1], bfr[1], acc[mf][0]);
    }
    __builtin_amdgcn_s_setprio(0);
    __builtin_amdgcn_s_barrier();
    // ---- P1: all m x n23 ----
    bfr[0] = *(const bf16x8*)(bufp + boff[1] + colx0);
    bfr[1] = *(const bf16x8*)(bufp + boff[1] + colx1);
    if (t + 2 < NT) STG_A(t + 2);
    GATE();
    __builtin_amdgcn_s_setprio(1);
#pragma unroll
    for (int mf = 0; mf < 4; mf++) {
      acc[mf][1] = MFMA_BF16(af[mf][0], bfr[0], acc[mf][1]);
      acc[mf][1] = MFMA_BF16(af[mf][1], bfr[1], acc[mf][1]);
    }
    __builtin_amdgcn_s_setprio(0);
    if (t + 2 < NT)      { asm volatile("s_waitcnt vmcnt(2)" ::: "memory"); }
    else if (t + 1 < NT) { asm volatile("s_waitcnt vmcnt(0)" ::: "memory"); }
    __builtin_amdgcn_s_barrier();
  }
#undef STG_A
#undef STG_B
#undef GATE

  // epilogue: row = m0+wm*64+mf*16+kgrp*4+r, col = n0+nf*64+wn*16+row16
#pragma unroll
  for (int mf = 0; mf < 4; mf++) {
    const int rowb = m0 + wm * 64 + mf * 16 + kgrp * 4;
#pragma unroll
    for (int nf = 0; nf < 2; nf++) {
      const int col = n0 + nf * 64 + wn * 16 + row16;
#pragma unroll
      for (int r = 0; r < 4; r++) {
        const float v = acc[mf][nf][r];
        const int rr2 = rowb + r;
        if constexpr (EPI == 0) {
          const int bbx = rr2 >> 10, s = rr2 & 1023;
          if (col < 1024) {
            const int hh = col >> 6, d = col & 63;
            qb[(((size_t)(bbx * NH_ + hh)) * S_ + s) * HD_ + d] = (bf16_t)(v * 0.125f);
          } else if (col < 2048) {
            const int c = col - 1024, hh = c >> 6, d = c & 63;
            kb[(((size_t)(bbx * NH_ + hh)) * S_ + s) * HD_ + d] = (bf16_t)v;
          } else {
            const int c = col - 2048, hh = c >> 6, d = c & 63;
            vtb[(((size_t)(bbx * NH_ + hh)) * HD_ + d) * S_ + s] = (bf16_t)v;
          }
        } else if constexpr (EPI == 1) {
          fout[(size_t)rr2 * N + col] += v;
        } else if constexpr (EPI == 2) {
          bout[(size_t)rr2 * N + col] = (bf16_t)fmaxf(v + bias[col], 0.0f);
        } else if constexpr (EPI == 3) {
          fout[(size_t)rr2 * N + col] += v + bias[col];
        } else {
          fout[(size_t)rr2 * N + col] = v + bias[col];
        }
      }
    }
  }
}

// ---------------------------------------------------------------------------
// Flash attention (causal), KVBLK=64, latency-pipelined (r9 structure) +
// MFMA-computed denominator (r11, neutral-verified): accL = P @ ones.
// ---------------------------------------------------------------------------
__global__ __launch_bounds__(256, 3) void attn_flash(const bf16_t* __restrict__ qg,
                                                     const bf16_t* __restrict__ kg,
                                                     const bf16_t* __restrict__ vtg,
                                                     bf16_t* __restrict__ aout) {
  const int nb = gridDim.x;
  const int logical = ((blockIdx.x & 7) * (nb >> 3)) + (blockIdx.x >> 3);
  const int qtile = logical & 15;
  const int bh    = logical >> 4;
  const int tid = threadIdx.x;
  const int wave = tid >> 6, lane = tid & 63;
  const int row16 = lane & 15, kgrp = lane >> 4;
  const int q0 = qtile * 64 + wave * 16;

  const bf16_t* qb = qg + (size_t)bh * S_ * HD_;
  const bf16_t* kb = kg + (size_t)bh * S_ * HD_;
  const bf16_t* vb = vtg + (size_t)bh * HD_ * S_;

  const bf16x8 qf0 = *(const bf16x8*)&qb[(size_t)(q0 + row16) * HD_ + kgrp * 8];
  const bf16x8 qf1 = *(const bf16x8*)&qb[(size_t)(q0 + row16) * HD_ + 32 + kgrp * 8];

  f32x4 accO[4] = {};
  f32x4 accL = {};
  float mrun[4] = {-1e30f, -1e30f, -1e30f, -1e30f};

  bf16x8 ones;
#pragma unroll
  for (int i = 0; i < 8; i++) ones[i] = (bf16_t)1.0f;

  __shared__ char sP[4][2048];
  char* const sw = &sP[wave][0];

  const int NTt = qtile + 1;

  bf16x8 kf[4][2];
#pragma unroll
  for (int q = 0; q < 4; q++) {
    kf[q][0] = *(const bf16x8*)&kb[(size_t)(q * 16 + row16) * HD_ + kgrp * 8];
    kf[q][1] = *(const bf16x8*)&kb[(size_t)(q * 16 + row16) * HD_ + 32 + kgrp * 8];
  }

  for (int t = 0; t < NTt; ++t) {
    const int k0 = t * 64;
    f32x4 sc[4];
#pragma unroll
    for (int q = 0; q < 4; q++) {
      f32x4 z = {};
      z = MFMA_BF16(qf0, kf[q][0], z);
      sc[q] = MFMA_BF16(qf1, kf[q][1], z);
    }
    bf16x8 vf[4][2];
#pragma unroll
    for (int d = 0; d < 4; d++) {
      vf[d][0] = *(const bf16x8*)&vb[(size_t)(d * 16 + row16) * S_ + k0 + kgrp * 8];
      vf[d][1] = *(const bf16x8*)&vb[(size_t)(d * 16 + row16) * S_ + k0 + 32 + kgrp * 8];
    }
    const bool diag = (k0 + 64 > q0);
    float p[4][4];
#pragma unroll
    for (int r = 0; r < 4; r++) {
      const int qglob = q0 + kgrp * 4 + r;
      float s0 = sc[0][r], s1 = sc[1][r], s2 = sc[2][r], s3 = sc[3][r];
      if (diag) {
        s0 = (k0 + row16 <= qglob) ? s0 : -1e30f;
        s1 = (k0 + 16 + row16 <= qglob) ? s1 : -1e30f;
        s2 = (k0 + 32 + row16 <= qglob) ? s2 : -1e30f;
        s3 = (k0 + 48 + row16 <= qglob) ? s3 : -1e30f;
      }
      float tmax = fmaxf(fmaxf(s0, s1), fmaxf(s2, s3));
#pragma unroll
      for (int msk = 1; msk < 16; msk <<= 1) tmax = fmaxf(tmax, __shfl_xor(tmax, msk, 64));
      const float mnew  = fmaxf(mrun[r], tmax);
      const float alpha = __expf(mrun[r] - mnew);
      mrun[r] = mnew;
      p[r][0] = __expf(s0 - mnew);
      p[r][1] = __expf(s1 - mnew);
      p[r][2] = __expf(s2 - mnew);
      p[r][3] = __expf(s3 - mnew);
      accL[r] *= alpha;
#pragma unroll
      for (int d = 0; d < 4; d++) accO[d][r] *= alpha;
    }
    if (t + 1 < NTt) {
      const int k0n = k0 + 64;
#pragma unroll
      for (int q = 0; q < 4; q++) {
        kf[q][0] = *(const bf16x8*)&kb[(size_t)(k0n + q * 16 + row16) * HD_ + kgrp * 8];
        kf[q][1] = *(const bf16x8*)&kb[(size_t)(k0n + q * 16 + row16) * HD_ + 32 + kgrp * 8];
      }
    }
#pragma unroll
    for (int r = 0; r < 4; r++) {
      const int prow = kgrp * 4 + r;
      const int px = (prow & 7) << 4;
#pragma unroll
      for (int q = 0; q < 4; q++) {
        *(bf16_t*)(sw + prow * 128 + (((q * 16 + row16) * 2) ^ px)) = (bf16_t)p[r][q];
      }
    }
    const int rx = (row16 & 7) << 4;
    const bf16x8 pf0 = *(const bf16x8*)(sw + row16 * 128 + ((kgrp * 16) ^ rx));
    const bf16x8 pf1 = *(const bf16x8*)(sw + row16 * 128 + ((64 + kgrp * 16) ^ rx));
    accL = MFMA_BF16(pf0, ones, accL);
    accL = MFMA_BF16(pf1, ones, accL);
#pragma unroll
    for (int d = 0; d < 4; d++) {
      accO[d] = MFMA_BF16(pf0, vf[d][0], accO[d]);
      accO[d] = MFMA_BF16(pf1, vf[d][1], accO[d]);
    }
  }

  float rinv[4];
#pragma unroll
  for (int r = 0; r < 4; r++) rinv[r] = 1.0f / accL[r];
  const int b = bh >> 4, hh = bh & 15;
#pragma unroll
  for (int d = 0; d < 4; d++)
#pragma unroll
    for (int r = 0; r < 4; r++) {
      const int tok = b * S_ + q0 + kgrp * 4 + r;
      aout[(size_t)tok * D_ + hh * HD_ + d * 16 + row16] = (bf16_t)(accO[d][r] * rinv[r]);
    }
}

// ---------------------------------------------------------------------------
// Launch
// ---------------------------------------------------------------------------
extern "C" void kernel_launch(void* const* d_in, const int* in_sizes, int n_in,
                              void* d_out, int out_size, void* d_ws, size_t ws_size,
                              hipStream_t stream) {
  const int*   x      = (const int*)d_in[0];
  const float* emb_W  = (const float*)d_in[1];
  const float* q_W    = (const float*)d_in[2];
  const float* k_W    = (const float*)d_in[3];
  const float* v_W    = (const float*)d_in[4];
  const float* o_W    = (const float*)d_in[5];
  const float* ln0_g  = (const float*)d_in[6];
  const float* ln0_b  = (const float*)d_in[7];
  const float* ln1_g  = (const float*)d_in[8];
  const float* ln1_b  = (const float*)d_in[9];
  const float* ffn_W1 = (const float*)d_in[10];
  const float* ffn_b1 = (const float*)d_in[11];
  const float* ffn_W2 = (const float*)d_in[12];
  const float* ffn_b2 = (const float*)d_in[13];
  const float* out_W  = (const float*)d_in[14];
  const float* out_b  = (const float*)d_in[15];
  float* out = (float*)d_out;

  char* p = (char*)d_ws;
  auto take = [&](size_t n) { char* r = p; p += (n + 255) & ~(size_t)255; return r; };
  float*  pe    = (float*)take((size_t)S_ * D_ * 4);
  float*  h     = (float*)take((size_t)TOK_ * D_ * 4);
  bf16_t* ain   = (bf16_t*)take((size_t)TOK_ * D_ * 2);
  bf16_t* attno = (bf16_t*)take((size_t)TOK_ * D_ * 2);
  bf16_t* qb    = (bf16_t*)take((size_t)B_ * NH_ * S_ * HD_ * 2);
  bf16_t* kb    = (bf16_t*)take((size_t)B_ * NH_ * S_ * HD_ * 2);
  bf16_t* vtb   = (bf16_t*)take((size_t)B_ * NH_ * S_ * HD_ * 2);
  bf16_t* ff    = (bf16_t*)take((size_t)TOK_ * HF_ * 2);
  bf16_t* qkvW  = (bf16_t*)take((size_t)3 * D_ * D_ * 2);
  bf16_t* oWb   = (bf16_t*)take((size_t)D_ * D_ * 2);
  bf16_t* W1b   = (bf16_t*)take((size_t)HF_ * D_ * 2);
  bf16_t* W2b   = (bf16_t*)take((size_t)D_ * HF_ * 2);
  bf16_t* outWb = (bf16_t*)take((size_t)V_ * D_ * 2);

  // --- weights -> bf16 ---
  cvt_f32_bf16<<<1024, 256, 0, stream>>>(q_W, qkvW, D_ * D_ / 4);
  cvt_f32_bf16<<<1024, 256, 0, stream>>>(k_W, qkvW + (size_t)D_ * D_, D_ * D_ / 4);
  cvt_f32_bf16<<<1024, 256, 0, stream>>>(v_W, qkvW + (size_t)2 * D_ * D_, D_ * D_ / 4);
  cvt_f32_bf16<<<1024, 256, 0, stream>>>(o_W, oWb, D_ * D_ / 4);
  cvt_f32_bf16<<<4096, 256, 0, stream>>>(ffn_W1, W1b, HF_ * D_ / 4);
  cvt_f32_bf16<<<4096, 256, 0, stream>>>(ffn_W2, W2b, D_ * HF_ / 4);
  cvt_f32_bf16<<<32000, 256, 0, stream>>>(out_W, outWb, V_ * D_ / 4);

  // --- embedding + PE ---
  pe_kernel<<<S_, 256, 0, stream>>>(pe);
  embed_kernel<<<TOK_ * D_ / 4 / 256, 256, 0, stream>>>(x, emb_W, pe, h);

  // --- transformer blocks (shared weights) ---
  for (int blk = 0; blk < 4; blk++) {
    ln_res_kernel<<<TOK_, 256, 0, stream>>>(h, ln0_g, ln0_b, ain);
    gemm_sq<0><<<32 * (3 * D_ / 128), 512, 0, stream>>>(
        ain, qkvW, 3 * D_, D_, 3 * D_ / 128, 32, nullptr, nullptr, nullptr, qb, kb, vtb);
    attn_flash<<<16 * B_ * NH_, 256, 0, stream>>>(qb, kb, vtb, attno);
    gemm_sq<1><<<32 * (D_ / 128), 512, 0, stream>>>(
        attno, oWb, D_, D_, D_ / 128, 32, h, nullptr, nullptr, nullptr, nullptr, nullptr);
    ln_res_kernel<<<TOK_, 256, 0, stream>>>(h, ln1_g, ln1_b, ain);
    gemm_sq<2><<<32 * (HF_ / 128), 512, 0, stream>>>(
        ain, W1b, HF_, D_, HF_ / 128, 32, nullptr, ffn_b1, ff, nullptr, nullptr, nullptr);
    gemm_sq<3><<<32 * (D_ / 128), 512, 0, stream>>>(
        ff, W2b, D_, HF_, D_ / 128, 32, h, ffn_b2, nullptr, nullptr, nullptr, nullptr);
  }

  // --- final logits: per-XCD static M-ownership (band_n=250, mch=4):
  //     each XCD holds 1 MB of A L2-resident and sweeps all N; B via L3 ---
  cvt_f32_bf16<<<4096, 256, 0, stream>>>(h, ain, TOK_ * D_ / 4);
  gemm_sq<4><<<32 * (V_ / 128), 512, 0, stream>>>(
      ain, outWb, V_, D_, 250, 4, out, out_b, nullptr, nullptr, nullptr, nullptr);
}

// Round 15
// 1474.614 us; speedup vs baseline: 1.0758x; 1.0758x over previous
//
#include <hip/hip_runtime.h>
#include <hip/hip_bf16.h>
#include <math.h>

// ---------------------------------------------------------------------------
// Types
// ---------------------------------------------------------------------------
typedef __bf16 bf16_t;
typedef __bf16 bf16x8 __attribute__((ext_vector_type(8)));
typedef __bf16 bf16x4 __attribute__((ext_vector_type(4)));
typedef float  f32x4  __attribute__((ext_vector_type(4)));

#define MFMA_BF16(a, b, c) __builtin_amdgcn_mfma_f32_16x16x32_bf16((a), (b), (c), 0, 0, 0)

typedef const void __attribute__((address_space(1)))* gas_ptr;
typedef void       __attribute__((address_space(3)))* las_ptr;

__device__ __forceinline__ void gload_lds16(const void* g, void* l) {
  // global -> LDS direct, 16B per lane. LDS dest is wave-uniform base + lane*16.
  __builtin_amdgcn_global_load_lds((gas_ptr)g, (las_ptr)l, 16, 0, 0);
}

// ---------------------------------------------------------------------------
// Model constants
// ---------------------------------------------------------------------------
static constexpr int B_ = 4, S_ = 1024, D_ = 1024, HF_ = 4096, V_ = 32000;
static constexpr int NH_ = 16, HD_ = 64;
static constexpr int TOK_ = B_ * S_;  // 4096

// ---------------------------------------------------------------------------
// fp32 -> bf16 conversion (vectorized x4)
// ---------------------------------------------------------------------------
__global__ __launch_bounds__(256) void cvt_f32_bf16(const float* __restrict__ in,
                                                    bf16_t* __restrict__ out, int n4) {
  int i = blockIdx.x * 256 + threadIdx.x;
  if (i < n4) {
    float4 v = ((const float4*)in)[i];
    bf16x4 o;
    o[0] = (bf16_t)v.x; o[1] = (bf16_t)v.y; o[2] = (bf16_t)v.z; o[3] = (bf16_t)v.w;
    ((bf16x4*)out)[i] = o;
  }
}

// ---------------------------------------------------------------------------
// Sinusoidal positional encoding table
// ---------------------------------------------------------------------------
__global__ __launch_bounds__(256) void pe_kernel(float* __restrict__ pe) {
  const int s = blockIdx.x;
  for (int i = threadIdx.x; i < D_ / 2; i += 256) {
    float div = expf((2.0f * (float)i) * (-9.210340371976184f / (float)D_)); // ln(10000)
    float a = (float)s * div;
    pe[(size_t)s * D_ + 2 * i]     = sinf(a);
    pe[(size_t)s * D_ + 2 * i + 1] = cosf(a);
  }
}

// ---------------------------------------------------------------------------
// Embedding: h[t][d] = emb_W[x[t]][d] * 32 + pe[t % S][d]
// ---------------------------------------------------------------------------
__global__ __launch_bounds__(256) void embed_kernel(const int* __restrict__ x,
                                                    const float* __restrict__ embW,
                                                    const float* __restrict__ pe,
                                                    float* __restrict__ h) {
  int i = blockIdx.x * 256 + threadIdx.x;
  int token = i >> 8;
  int c4 = i & 255;
  int idx = x[token];
  float4 e = ((const float4*)(embW + (size_t)idx * D_))[c4];
  float4 p = ((const float4*)(pe + (size_t)(token & (S_ - 1)) * D_))[c4];
  float4 o;
  o.x = e.x * 32.0f + p.x; o.y = e.y * 32.0f + p.y;
  o.z = e.z * 32.0f + p.z; o.w = e.w * 32.0f + p.w;
  ((float4*)(h + (size_t)token * D_))[c4] = o;
}

// ---------------------------------------------------------------------------
// a_in = h + LayerNorm(h)*g + b   -> bf16
// ---------------------------------------------------------------------------
__global__ __launch_bounds__(256) void ln_res_kernel(const float* __restrict__ h,
                                                     const float* __restrict__ gamma,
                                                     const float* __restrict__ beta,
                                                     bf16_t* __restrict__ out) {
  const int row = blockIdx.x;
  const int tid = threadIdx.x;
  const float4 v = ((const float4*)(h + (size_t)row * D_))[tid];
  float s  = v.x + v.y + v.z + v.w;
  float s2 = v.x * v.x + v.y * v.y + v.z * v.z + v.w * v.w;
#pragma unroll
  for (int m = 1; m < 64; m <<= 1) {
    s  += __shfl_xor(s, m, 64);
    s2 += __shfl_xor(s2, m, 64);
  }
  __shared__ float red[2][4];
  const int wave = tid >> 6, lane = tid & 63;
  if (lane == 0) { red[0][wave] = s; red[1][wave] = s2; }
  __syncthreads();
  s  = red[0][0] + red[0][1] + red[0][2] + red[0][3];
  s2 = red[1][0] + red[1][1] + red[1][2] + red[1][3];
  const float mu   = s * (1.0f / D_);
  const float rstd = rsqrtf(s2 * (1.0f / D_) - mu * mu + 1e-5f);
  const float4 g4 = ((const float4*)gamma)[tid];
  const float4 b4 = ((const float4*)beta)[tid];
  bf16x4 o;
  o[0] = (bf16_t)(v.x + (v.x - mu) * rstd * g4.x + b4.x);
  o[1] = (bf16_t)(v.y + (v.y - mu) * rstd * g4.y + b4.y);
  o[2] = (bf16_t)(v.z + (v.z - mu) * rstd * g4.z + b4.z);
  o[3] = (bf16_t)(v.w + (v.w - mu) * rstd * g4.w + b4.w);
  ((bf16x4*)(out + (size_t)row * D_))[tid] = o;
}

// ---------------------------------------------------------------------------
// gemm_sq: 128x128 tile, BK=64, 2 phases/K-tile, 2 blocks/CU (verified r10).
// C[4096,N] = A[4096,K] @ W[N,K]^T. 8 waves (2M x 4N); per-wave 64x32.
// LDS 2 x 32 KB dbuf; launch_bounds(512,4) => 2 blocks/CU; sibling block
// covers barrier/drain/epilogue stalls. Counted vmcnt(2), never 0 mid-loop.
// Swizzle: 128B rows, byte ^ ((row&7)<<4), involution. XCD swizzle +
// 2-D SUPERTILE ordering (verified r13: logits FETCH 1.03GB->0.37GB,
// 464->324us; r14 falsified per-XCD static M-ownership: live working set
// must match L2 CONCURRENTLY - supertile size == concurrent blocks/XCD).
// Sizing rule: live set = mch*256KB (A) + band_n*256KB (B) <= 4MB with
// band_n*mch ~= 64 (concurrent blocks per XCD at 2/CU).
//   logits: (10,4); QKV/FFN1 (K=1024): (8,8); N=1024 shapes: identity decode.
// Epilogues: 0 QKV-scatter, 1 fout+=v, 2 relu(v+bias)->bf16, 3 fout+=v+bias,
//            4 fout = v + bias (pure store, logits).
// ---------------------------------------------------------------------------
template <int EPI>
__global__ __launch_bounds__(512, 4) void gemm_sq(
    const bf16_t* __restrict__ A, const bf16_t* __restrict__ W, int N, int K,
    int band_n, int mch,
    float* __restrict__ fout, const float* __restrict__ bias, bf16_t* __restrict__ bout,
    bf16_t* __restrict__ qb, bf16_t* __restrict__ kb, bf16_t* __restrict__ vtb) {
  __shared__ char lds[2][32768];

  const int tid = threadIdx.x;
  const int wave = tid >> 6, lane = tid & 63;
  const int row16 = lane & 15, kgrp = lane >> 4;
  const int wm = wave >> 2, wn = wave & 3;  // 2M x 4N

  const int nb = gridDim.x;  // multiple of 8
  const int logical = (blockIdx.x & 7) * (nb >> 3) + (blockIdx.x >> 3);
  // supertile decode: {band of band_n N-tiles} x {chunk of mch M-tiles},
  // M fastest within supertile; chunks inner, bands outer. (M = 32 tiles)
  const int st = band_n * mch;
  const int stid = logical / st;
  const int rr = logical - stid * st;
  const int nMch = 32 / mch;
  const int band = stid / nMch;
  const int mchid = stid - band * nMch;
  const int m0 = (mchid * mch + (rr % mch)) << 7;
  const int n0 = (band * band_n + rr / mch) << 7;
  const size_t K2 = (size_t)K * 2;

  const int lr = lane >> 3;
  const int swz = ((lane & 7) * 16) ^ (lr << 4);
  const char* gA = (const char*)A + (size_t)(m0 + wave * 8 + lr) * K2 + swz;
  const char* gB = (const char*)W + (size_t)(n0 + wave * 8 + lr) * K2 + swz;
  char* const ldsc = &lds[0][0];
  const int dW = wave * 1024;

#define STG_A(v)                                                  \
  { char* d_ = ldsc + (((v) & 1) << 15) + dW;                     \
    const char* g_ = gA + (size_t)(v) * 128;                      \
    gload_lds16(g_, d_); gload_lds16(g_ + 64 * K2, d_ + 8192); }
#define STG_B(v)                                                  \
  { char* d_ = ldsc + (((v) & 1) << 15) + 16384 + dW;             \
    const char* g_ = gB + (size_t)(v) * 128;                      \
    gload_lds16(g_, d_); gload_lds16(g_ + 64 * K2, d_ + 8192); }

  const int colx0 = (kgrp * 16) ^ ((row16 & 7) << 4);
  const int colx1 = (64 + kgrp * 16) ^ ((row16 & 7) << 4);
  int aoff[4], boff[2];
#pragma unroll
  for (int mf = 0; mf < 4; mf++) aoff[mf] = (wm * 64 + mf * 16 + row16) * 128;
#pragma unroll
  for (int nf = 0; nf < 2; nf++) boff[nf] = 16384 + (nf * 64 + wn * 16 + row16) * 128;

#define GATE()                                        \
  __builtin_amdgcn_s_barrier();                       \
  asm volatile("s_waitcnt lgkmcnt(0)" ::: "memory");  \
  __builtin_amdgcn_sched_barrier(0);

  f32x4 acc[4][2] = {};
  bf16x8 af[4][2], bfr[2];
  const int NT = K >> 6;

  STG_A(0); STG_B(0); STG_A(1);
  asm volatile("s_waitcnt vmcnt(2)" ::: "memory");  // A(0), B(0) landed
  __builtin_amdgcn_s_barrier();

  for (int t = 0; t < NT; ++t) {
    const char* bufp = ldsc + ((t & 1) << 15);
    // ---- P0: all m x n01 ----
#pragma unroll
    for (int mf = 0; mf < 4; mf++) {
      af[mf][0] = *(const bf16x8*)(bufp + aoff[mf] + colx0);
      af[mf][1] = *(const bf16x8*)(bufp + aoff[mf] + colx1);
    }
    bfr[0] = *(const bf16x8*)(bufp + boff[0] + colx0);
    bfr[1] = *(const bf16x8*)(bufp + boff[0] + colx1);
    if (t + 1 < NT) STG_B(t + 1);
    GATE();
    __builtin_amdgcn_s_setprio(1);
#pragma unroll
    for (int mf = 0; mf < 4; mf++) {
      acc[mf][0] = MFMA_BF16(af[mf][0], bfr[0], acc[mf][0]);
      acc[mf][0] = MFMA_BF16(af[mf][1], bfr[1], acc[mf][0]);
    }
    __builtin_amdgcn_s_setprio(0);
    __builtin_amdgcn_s_barrier();
    // ---- P1: all m x n23 ----
    bfr[0] = *(const bf16x8*)(bufp + boff[1] + colx0);
    bfr[1] = *(const bf16x8*)(bufp + boff[1] + colx1);
    if (t + 2 < NT) STG_A(t + 2);
    GATE();
    __builtin_amdgcn_s_setprio(1);
#pragma unroll
    for (int mf = 0; mf < 4; mf++) {
      acc[mf][1] = MFMA_BF16(af[mf][0], bfr[0], acc[mf][1]);
      acc[mf][1] = MFMA_BF16(af[mf][1], bfr[1], acc[mf][1]);
    }
    __builtin_amdgcn_s_setprio(0);
    if (t + 2 < NT)      { asm volatile("s_waitcnt vmcnt(2)" ::: "memory"); }
    else if (t + 1 < NT) { asm volatile("s_waitcnt vmcnt(0)" ::: "memory"); }
    __builtin_amdgcn_s_barrier();
  }
#undef STG_A
#undef STG_B
#undef GATE

  // epilogue: row = m0+wm*64+mf*16+kgrp*4+r, col = n0+nf*64+wn*16+row16
#pragma unroll
  for (int mf = 0; mf < 4; mf++) {
    const int rowb = m0 + wm * 64 + mf * 16 + kgrp * 4;
#pragma unroll
    for (int nf = 0; nf < 2; nf++) {
      const int col = n0 + nf * 64 + wn * 16 + row16;
#pragma unroll
      for (int r = 0; r < 4; r++) {
        const float v = acc[mf][nf][r];
        const int rr2 = rowb + r;
        if constexpr (EPI == 0) {
          const int bbx = rr2 >> 10, s = rr2 & 1023;
          if (col < 1024) {
            const int hh = col >> 6, d = col & 63;
            qb[(((size_t)(bbx * NH_ + hh)) * S_ + s) * HD_ + d] = (bf16_t)(v * 0.125f);
          } else if (col < 2048) {
            const int c = col - 1024, hh = c >> 6, d = c & 63;
            kb[(((size_t)(bbx * NH_ + hh)) * S_ + s) * HD_ + d] = (bf16_t)v;
          } else {
            const int c = col - 2048, hh = c >> 6, d = c & 63;
            vtb[(((size_t)(bbx * NH_ + hh)) * HD_ + d) * S_ + s] = (bf16_t)v;
          }
        } else if constexpr (EPI == 1) {
          fout[(size_t)rr2 * N + col] += v;
        } else if constexpr (EPI == 2) {
          bout[(size_t)rr2 * N + col] = (bf16_t)fmaxf(v + bias[col], 0.0f);
        } else if constexpr (EPI == 3) {
          fout[(size_t)rr2 * N + col] += v + bias[col];
        } else {
          fout[(size_t)rr2 * N + col] = v + bias[col];
        }
      }
    }
  }
}

// ---------------------------------------------------------------------------
// Flash attention (causal), KVBLK=64, latency-pipelined (r9 structure) +
// MFMA-computed denominator (r11, neutral-verified): accL = P @ ones.
// ---------------------------------------------------------------------------
__global__ __launch_bounds__(256, 3) void attn_flash(const bf16_t* __restrict__ qg,
                                                     const bf16_t* __restrict__ kg,
                                                     const bf16_t* __restrict__ vtg,
                                                     bf16_t* __restrict__ aout) {
  const int nb = gridDim.x;
  const int logical = ((blockIdx.x & 7) * (nb >> 3)) + (blockIdx.x >> 3);
  const int qtile = logical & 15;
  const int bh    = logical >> 4;
  const int tid = threadIdx.x;
  const int wave = tid >> 6, lane = tid & 63;
  const int row16 = lane & 15, kgrp = lane >> 4;
  const int q0 = qtile * 64 + wave * 16;

  const bf16_t* qb = qg + (size_t)bh * S_ * HD_;
  const bf16_t* kb = kg + (size_t)bh * S_ * HD_;
  const bf16_t* vb = vtg + (size_t)bh * HD_ * S_;

  const bf16x8 qf0 = *(const bf16x8*)&qb[(size_t)(q0 + row16) * HD_ + kgrp * 8];
  const bf16x8 qf1 = *(const bf16x8*)&qb[(size_t)(q0 + row16) * HD_ + 32 + kgrp * 8];

  f32x4 accO[4] = {};
  f32x4 accL = {};
  float mrun[4] = {-1e30f, -1e30f, -1e30f, -1e30f};

  bf16x8 ones;
#pragma unroll
  for (int i = 0; i < 8; i++) ones[i] = (bf16_t)1.0f;

  __shared__ char sP[4][2048];
  char* const sw = &sP[wave][0];

  const int NTt = qtile + 1;

  bf16x8 kf[4][2];
#pragma unroll
  for (int q = 0; q < 4; q++) {
    kf[q][0] = *(const bf16x8*)&kb[(size_t)(q * 16 + row16) * HD_ + kgrp * 8];
    kf[q][1] = *(const bf16x8*)&kb[(size_t)(q * 16 + row16) * HD_ + 32 + kgrp * 8];
  }

  for (int t = 0; t < NTt; ++t) {
    const int k0 = t * 64;
    f32x4 sc[4];
#pragma unroll
    for (int q = 0; q < 4; q++) {
      f32x4 z = {};
      z = MFMA_BF16(qf0, kf[q][0], z);
      sc[q] = MFMA_BF16(qf1, kf[q][1], z);
    }
    bf16x8 vf[4][2];
#pragma unroll
    for (int d = 0; d < 4; d++) {
      vf[d][0] = *(const bf16x8*)&vb[(size_t)(d * 16 + row16) * S_ + k0 + kgrp * 8];
      vf[d][1] = *(const bf16x8*)&vb[(size_t)(d * 16 + row16) * S_ + k0 + 32 + kgrp * 8];
    }
    const bool diag = (k0 + 64 > q0);
    float p[4][4];
#pragma unroll
    for (int r = 0; r < 4; r++) {
      const int qglob = q0 + kgrp * 4 + r;
      float s0 = sc[0][r], s1 = sc[1][r], s2 = sc[2][r], s3 = sc[3][r];
      if (diag) {
        s0 = (k0 + row16 <= qglob) ? s0 : -1e30f;
        s1 = (k0 + 16 + row16 <= qglob) ? s1 : -1e30f;
        s2 = (k0 + 32 + row16 <= qglob) ? s2 : -1e30f;
        s3 = (k0 + 48 + row16 <= qglob) ? s3 : -1e30f;
      }
      float tmax = fmaxf(fmaxf(s0, s1), fmaxf(s2, s3));
#pragma unroll
      for (int msk = 1; msk < 16; msk <<= 1) tmax = fmaxf(tmax, __shfl_xor(tmax, msk, 64));
      const float mnew  = fmaxf(mrun[r], tmax);
      const float alpha = __expf(mrun[r] - mnew);
      mrun[r] = mnew;
      p[r][0] = __expf(s0 - mnew);
      p[r][1] = __expf(s1 - mnew);
      p[r][2] = __expf(s2 - mnew);
      p[r][3] = __expf(s3 - mnew);
      accL[r] *= alpha;
#pragma unroll
      for (int d = 0; d < 4; d++) accO[d][r] *= alpha;
    }
    if (t + 1 < NTt) {
      const int k0n = k0 + 64;
#pragma unroll
      for (int q = 0; q < 4; q++) {
        kf[q][0] = *(const bf16x8*)&kb[(size_t)(k0n + q * 16 + row16) * HD_ + kgrp * 8];
        kf[q][1] = *(const bf16x8*)&kb[(size_t)(k0n + q * 16 + row16) * HD_ + 32 + kgrp * 8];
      }
    }
#pragma unroll
    for (int r = 0; r < 4; r++) {
      const int prow = kgrp * 4 + r;
      const int px = (prow & 7) << 4;
#pragma unroll
      for (int q = 0; q < 4; q++) {
        *(bf16_t*)(sw + prow * 128 + (((q * 16 + row16) * 2) ^ px)) = (bf16_t)p[r][q];
      }
    }
    const int rx = (row16 & 7) << 4;
    const bf16x8 pf0 = *(const bf16x8*)(sw + row16 * 128 + ((kgrp * 16) ^ rx));
    const bf16x8 pf1 = *(const bf16x8*)(sw + row16 * 128 + ((64 + kgrp * 16) ^ rx));
    accL = MFMA_BF16(pf0, ones, accL);
    accL = MFMA_BF16(pf1, ones, accL);
#pragma unroll
    for (int d = 0; d < 4; d++) {
      accO[d] = MFMA_BF16(pf0, vf[d][0], accO[d]);
      accO[d] = MFMA_BF16(pf1, vf[d][1], accO[d]);
    }
  }

  float rinv[4];
#pragma unroll
  for (int r = 0; r < 4; r++) rinv[r] = 1.0f / accL[r];
  const int b = bh >> 4, hh = bh & 15;
#pragma unroll
  for (int d = 0; d < 4; d++)
#pragma unroll
    for (int r = 0; r < 4; r++) {
      const int tok = b * S_ + q0 + kgrp * 4 + r;
      aout[(size_t)tok * D_ + hh * HD_ + d * 16 + row16] = (bf16_t)(accO[d][r] * rinv[r]);
    }
}

// ---------------------------------------------------------------------------
// Launch
// ---------------------------------------------------------------------------
extern "C" void kernel_launch(void* const* d_in, const int* in_sizes, int n_in,
                              void* d_out, int out_size, void* d_ws, size_t ws_size,
                              hipStream_t stream) {
  const int*   x      = (const int*)d_in[0];
  const float* emb_W  = (const float*)d_in[1];
  const float* q_W    = (const float*)d_in[2];
  const float* k_W    = (const float*)d_in[3];
  const float* v_W    = (const float*)d_in[4];
  const float* o_W    = (const float*)d_in[5];
  const float* ln0_g  = (const float*)d_in[6];
  const float* ln0_b  = (const float*)d_in[7];
  const float* ln1_g  = (const float*)d_in[8];
  const float* ln1_b  = (const float*)d_in[9];
  const float* ffn_W1 = (const float*)d_in[10];
  const float* ffn_b1 = (const float*)d_in[11];
  const float* ffn_W2 = (const float*)d_in[12];
  const float* ffn_b2 = (const float*)d_in[13];
  const float* out_W  = (const float*)d_in[14];
  const float* out_b  = (const float*)d_in[15];
  float* out = (float*)d_out;

  char* p = (char*)d_ws;
  auto take = [&](size_t n) { char* r = p; p += (n + 255) & ~(size_t)255; return r; };
  float*  pe    = (float*)take((size_t)S_ * D_ * 4);
  float*  h     = (float*)take((size_t)TOK_ * D_ * 4);
  bf16_t* ain   = (bf16_t*)take((size_t)TOK_ * D_ * 2);
  bf16_t* attno = (bf16_t*)take((size_t)TOK_ * D_ * 2);
  bf16_t* qb    = (bf16_t*)take((size_t)B_ * NH_ * S_ * HD_ * 2);
  bf16_t* kb    = (bf16_t*)take((size_t)B_ * NH_ * S_ * HD_ * 2);
  bf16_t* vtb   = (bf16_t*)take((size_t)B_ * NH_ * S_ * HD_ * 2);
  bf16_t* ff    = (bf16_t*)take((size_t)TOK_ * HF_ * 2);
  bf16_t* qkvW  = (bf16_t*)take((size_t)3 * D_ * D_ * 2);
  bf16_t* oWb   = (bf16_t*)take((size_t)D_ * D_ * 2);
  bf16_t* W1b   = (bf16_t*)take((size_t)HF_ * D_ * 2);
  bf16_t* W2b   = (bf16_t*)take((size_t)D_ * HF_ * 2);
  bf16_t* outWb = (bf16_t*)take((size_t)V_ * D_ * 2);

  // --- weights -> bf16 ---
  cvt_f32_bf16<<<1024, 256, 0, stream>>>(q_W, qkvW, D_ * D_ / 4);
  cvt_f32_bf16<<<1024, 256, 0, stream>>>(k_W, qkvW + (size_t)D_ * D_, D_ * D_ / 4);
  cvt_f32_bf16<<<1024, 256, 0, stream>>>(v_W, qkvW + (size_t)2 * D_ * D_, D_ * D_ / 4);
  cvt_f32_bf16<<<1024, 256, 0, stream>>>(o_W, oWb, D_ * D_ / 4);
  cvt_f32_bf16<<<4096, 256, 0, stream>>>(ffn_W1, W1b, HF_ * D_ / 4);
  cvt_f32_bf16<<<4096, 256, 0, stream>>>(ffn_W2, W2b, D_ * HF_ / 4);
  cvt_f32_bf16<<<32000, 256, 0, stream>>>(out_W, outWb, V_ * D_ / 4);

  // --- embedding + PE ---
  pe_kernel<<<S_, 256, 0, stream>>>(pe);
  embed_kernel<<<TOK_ * D_ / 4 / 256, 256, 0, stream>>>(x, emb_W, pe, h);

  // --- transformer blocks (shared weights) ---
  for (int blk = 0; blk < 4; blk++) {
    ln_res_kernel<<<TOK_, 256, 0, stream>>>(h, ln0_g, ln0_b, ain);
    gemm_sq<0><<<32 * (3 * D_ / 128), 512, 0, stream>>>(
        ain, qkvW, 3 * D_, D_, 8, 8, nullptr, nullptr, nullptr, qb, kb, vtb);
    attn_flash<<<16 * B_ * NH_, 256, 0, stream>>>(qb, kb, vtb, attno);
    gemm_sq<1><<<32 * (D_ / 128), 512, 0, stream>>>(
        attno, oWb, D_, D_, D_ / 128, 32, h, nullptr, nullptr, nullptr, nullptr, nullptr);
    ln_res_kernel<<<TOK_, 256, 0, stream>>>(h, ln1_g, ln1_b, ain);
    gemm_sq<2><<<32 * (HF_ / 128), 512, 0, stream>>>(
        ain, W1b, HF_, D_, 8, 8, nullptr, ffn_b1, ff, nullptr, nullptr, nullptr);
    gemm_sq<3><<<32 * (D_ / 128), 512, 0, stream>>>(
        ff, W2b, D_, HF_, D_ / 128, 32, h, ffn_b2, nullptr, nullptr, nullptr, nullptr);
  }

  // --- final logits: supertile {10 N-tiles} x {4 M-tiles} (verified r13) ---
  cvt_f32_bf16<<<4096, 256, 0, stream>>>(h, ain, TOK_ * D_ / 4);
  gemm_sq<4><<<32 * (V_ / 128), 512, 0, stream>>>(
      ain, outWb, V_, D_, 10, 4, out, out_b, nullptr, nullptr, nullptr, nullptr);
}

// Round 16
// 1472.842 us; speedup vs baseline: 1.0771x; 1.0012x over previous
//
#include <hip/hip_runtime.h>
#include <hip/hip_bf16.h>
#include <math.h>

// ---------------------------------------------------------------------------
// Types
// ---------------------------------------------------------------------------
typedef __bf16 bf16_t;
typedef __bf16 bf16x8 __attribute__((ext_vector_type(8)));
typedef __bf16 bf16x4 __attribute__((ext_vector_type(4)));
typedef float  f32x4  __attribute__((ext_vector_type(4)));

#define MFMA_BF16(a, b, c) __builtin_amdgcn_mfma_f32_16x16x32_bf16((a), (b), (c), 0, 0, 0)

typedef const void __attribute__((address_space(1)))* gas_ptr;
typedef void       __attribute__((address_space(3)))* las_ptr;

__device__ __forceinline__ void gload_lds16(const void* g, void* l) {
  // global -> LDS direct, 16B per lane. LDS dest is wave-uniform base + lane*16.
  __builtin_amdgcn_global_load_lds((gas_ptr)g, (las_ptr)l, 16, 0, 0);
}

// ---------------------------------------------------------------------------
// Model constants
// ---------------------------------------------------------------------------
static constexpr int B_ = 4, S_ = 1024, D_ = 1024, HF_ = 4096, V_ = 32000;
static constexpr int NH_ = 16, HD_ = 64;
static constexpr int TOK_ = B_ * S_;  // 4096

// ---------------------------------------------------------------------------
// fp32 -> bf16 conversion (vectorized x4)
// ---------------------------------------------------------------------------
__global__ __launch_bounds__(256) void cvt_f32_bf16(const float* __restrict__ in,
                                                    bf16_t* __restrict__ out, int n4) {
  int i = blockIdx.x * 256 + threadIdx.x;
  if (i < n4) {
    float4 v = ((const float4*)in)[i];
    bf16x4 o;
    o[0] = (bf16_t)v.x; o[1] = (bf16_t)v.y; o[2] = (bf16_t)v.z; o[3] = (bf16_t)v.w;
    ((bf16x4*)out)[i] = o;
  }
}

// ---------------------------------------------------------------------------
// Sinusoidal positional encoding table
// ---------------------------------------------------------------------------
__global__ __launch_bounds__(256) void pe_kernel(float* __restrict__ pe) {
  const int s = blockIdx.x;
  for (int i = threadIdx.x; i < D_ / 2; i += 256) {
    float div = expf((2.0f * (float)i) * (-9.210340371976184f / (float)D_)); // ln(10000)
    float a = (float)s * div;
    pe[(size_t)s * D_ + 2 * i]     = sinf(a);
    pe[(size_t)s * D_ + 2 * i + 1] = cosf(a);
  }
}

// ---------------------------------------------------------------------------
// Embedding: h[t][d] = emb_W[x[t]][d] * 32 + pe[t % S][d]
// ---------------------------------------------------------------------------
__global__ __launch_bounds__(256) void embed_kernel(const int* __restrict__ x,
                                                    const float* __restrict__ embW,
                                                    const float* __restrict__ pe,
                                                    float* __restrict__ h) {
  int i = blockIdx.x * 256 + threadIdx.x;
  int token = i >> 8;
  int c4 = i & 255;
  int idx = x[token];
  float4 e = ((const float4*)(embW + (size_t)idx * D_))[c4];
  float4 p = ((const float4*)(pe + (size_t)(token & (S_ - 1)) * D_))[c4];
  float4 o;
  o.x = e.x * 32.0f + p.x; o.y = e.y * 32.0f + p.y;
  o.z = e.z * 32.0f + p.z; o.w = e.w * 32.0f + p.w;
  ((float4*)(h + (size_t)token * D_))[c4] = o;
}

// ---------------------------------------------------------------------------
// a_in = h + LayerNorm(h)*g + b   -> bf16
// ---------------------------------------------------------------------------
__global__ __launch_bounds__(256) void ln_res_kernel(const float* __restrict__ h,
                                                     const float* __restrict__ gamma,
                                                     const float* __restrict__ beta,
                                                     bf16_t* __restrict__ out) {
  const int row = blockIdx.x;
  const int tid = threadIdx.x;
  const float4 v = ((const float4*)(h + (size_t)row * D_))[tid];
  float s  = v.x + v.y + v.z + v.w;
  float s2 = v.x * v.x + v.y * v.y + v.z * v.z + v.w * v.w;
#pragma unroll
  for (int m = 1; m < 64; m <<= 1) {
    s  += __shfl_xor(s, m, 64);
    s2 += __shfl_xor(s2, m, 64);
  }
  __shared__ float red[2][4];
  const int wave = tid >> 6, lane = tid & 63;
  if (lane == 0) { red[0][wave] = s; red[1][wave] = s2; }
  __syncthreads();
  s  = red[0][0] + red[0][1] + red[0][2] + red[0][3];
  s2 = red[1][0] + red[1][1] + red[1][2] + red[1][3];
  const float mu   = s * (1.0f / D_);
  const float rstd = rsqrtf(s2 * (1.0f / D_) - mu * mu + 1e-5f);
  const float4 g4 = ((const float4*)gamma)[tid];
  const float4 b4 = ((const float4*)beta)[tid];
  bf16x4 o;
  o[0] = (bf16_t)(v.x + (v.x - mu) * rstd * g4.x + b4.x);
  o[1] = (bf16_t)(v.y + (v.y - mu) * rstd * g4.y + b4.y);
  o[2] = (bf16_t)(v.z + (v.z - mu) * rstd * g4.z + b4.z);
  o[3] = (bf16_t)(v.w + (v.w - mu) * rstd * g4.w + b4.w);
  ((bf16x4*)(out + (size_t)row * D_))[tid] = o;
}

// ---------------------------------------------------------------------------
// gemm_sq: 128x128 tile, BK=64, 2 phases/K-tile, 2 blocks/CU (verified r10).
// C[4096,N] = A[4096,K] @ W[N,K]^T. 8 waves (2M x 4N); per-wave 64x32.
// LDS 2 x 32 KB dbuf; launch_bounds(512,4) => 2 blocks/CU; sibling block
// covers barrier/drain/epilogue stalls. Counted vmcnt(2), never 0 mid-loop.
// Swizzle: 128B rows, byte ^ ((row&7)<<4), involution. XCD swizzle +
// 2-D SUPERTILE ordering (verified r13: logits FETCH 1.03GB->0.37GB,
// 464->324us; r14 falsified per-XCD static M-ownership: live working set
// must match L2 CONCURRENTLY - supertile size == concurrent blocks/XCD).
// Sizing rule: live set = mch*256KB (A) + band_n*256KB (B) <= 4MB with
// band_n*mch ~= 64 (concurrent blocks per XCD at 2/CU).
//   logits: (10,4); QKV/FFN1 (K=1024): (8,8); N=1024 shapes: identity decode.
// Epilogues: 0 QKV-scatter, 1 fout+=v, 2 relu(v+bias)->bf16, 3 fout+=v+bias,
//            4 fout = v + bias (pure store, logits).
// ---------------------------------------------------------------------------
template <int EPI>
__global__ __launch_bounds__(512, 4) void gemm_sq(
    const bf16_t* __restrict__ A, const bf16_t* __restrict__ W, int N, int K,
    int band_n, int mch,
    float* __restrict__ fout, const float* __restrict__ bias, bf16_t* __restrict__ bout,
    bf16_t* __restrict__ qb, bf16_t* __restrict__ kb, bf16_t* __restrict__ vtb) {
  __shared__ char lds[2][32768];

  const int tid = threadIdx.x;
  const int wave = tid >> 6, lane = tid & 63;
  const int row16 = lane & 15, kgrp = lane >> 4;
  const int wm = wave >> 2, wn = wave & 3;  // 2M x 4N

  const int nb = gridDim.x;  // multiple of 8
  const int logical = (blockIdx.x & 7) * (nb >> 3) + (blockIdx.x >> 3);
  // supertile decode: {band of band_n N-tiles} x {chunk of mch M-tiles},
  // M fastest within supertile; chunks inner, bands outer. (M = 32 tiles)
  const int st = band_n * mch;
  const int stid = logical / st;
  const int rr = logical - stid * st;
  const int nMch = 32 / mch;
  const int band = stid / nMch;
  const int mchid = stid - band * nMch;
  const int m0 = (mchid * mch + (rr % mch)) << 7;
  const int n0 = (band * band_n + rr / mch) << 7;
  const size_t K2 = (size_t)K * 2;

  const int lr = lane >> 3;
  const int swz = ((lane & 7) * 16) ^ (lr << 4);
  const char* gA = (const char*)A + (size_t)(m0 + wave * 8 + lr) * K2 + swz;
  const char* gB = (const char*)W + (size_t)(n0 + wave * 8 + lr) * K2 + swz;
  char* const ldsc = &lds[0][0];
  const int dW = wave * 1024;

#define STG_A(v)                                                  \
  { char* d_ = ldsc + (((v) & 1) << 15) + dW;                     \
    const char* g_ = gA + (size_t)(v) * 128;                      \
    gload_lds16(g_, d_); gload_lds16(g_ + 64 * K2, d_ + 8192); }
#define STG_B(v)                                                  \
  { char* d_ = ldsc + (((v) & 1) << 15) + 16384 + dW;             \
    const char* g_ = gB + (size_t)(v) * 128;                      \
    gload_lds16(g_, d_); gload_lds16(g_ + 64 * K2, d_ + 8192); }

  const int colx0 = (kgrp * 16) ^ ((row16 & 7) << 4);
  const int colx1 = (64 + kgrp * 16) ^ ((row16 & 7) << 4);
  int aoff[4], boff[2];
#pragma unroll
  for (int mf = 0; mf < 4; mf++) aoff[mf] = (wm * 64 + mf * 16 + row16) * 128;
#pragma unroll
  for (int nf = 0; nf < 2; nf++) boff[nf] = 16384 + (nf * 64 + wn * 16 + row16) * 128;

#define GATE()                                        \
  __builtin_amdgcn_s_barrier();                       \
  asm volatile("s_waitcnt lgkmcnt(0)" ::: "memory");  \
  __builtin_amdgcn_sched_barrier(0);

  f32x4 acc[4][2] = {};
  bf16x8 af[4][2], bfr[2];
  const int NT = K >> 6;

  STG_A(0); STG_B(0); STG_A(1);
  asm volatile("s_waitcnt vmcnt(2)" ::: "memory");  // A(0), B(0) landed
  __builtin_amdgcn_s_barrier();

  for (int t = 0; t < NT; ++t) {
    const char* bufp = ldsc + ((t & 1) << 15);
    // ---- P0: all m x n01 ----
#pragma unroll
    for (int mf = 0; mf < 4; mf++) {
      af[mf][0] = *(const bf16x8*)(bufp + aoff[mf] + colx0);
      af[mf][1] = *(const bf16x8*)(bufp + aoff[mf] + colx1);
    }
    bfr[0] = *(const bf16x8*)(bufp + boff[0] + colx0);
    bfr[1] = *(const bf16x8*)(bufp + boff[0] + colx1);
    if (t + 1 < NT) STG_B(t + 1);
    GATE();
    __builtin_amdgcn_s_setprio(1);
#pragma unroll
    for (int mf = 0; mf < 4; mf++) {
      acc[mf][0] = MFMA_BF16(af[mf][0], bfr[0], acc[mf][0]);
      acc[mf][0] = MFMA_BF16(af[mf][1], bfr[1], acc[mf][0]);
    }
    __builtin_amdgcn_s_setprio(0);
    __builtin_amdgcn_s_barrier();
    // ---- P1: all m x n23 ----
    bfr[0] = *(const bf16x8*)(bufp + boff[1] + colx0);
    bfr[1] = *(const bf16x8*)(bufp + boff[1] + colx1);
    if (t + 2 < NT) STG_A(t + 2);
    GATE();
    __builtin_amdgcn_s_setprio(1);
#pragma unroll
    for (int mf = 0; mf < 4; mf++) {
      acc[mf][1] = MFMA_BF16(af[mf][0], bfr[0], acc[mf][1]);
      acc[mf][1] = MFMA_BF16(af[mf][1], bfr[1], acc[mf][1]);
    }
    __builtin_amdgcn_s_setprio(0);
    if (t + 2 < NT)      { asm volatile("s_waitcnt vmcnt(2)" ::: "memory"); }
    else if (t + 1 < NT) { asm volatile("s_waitcnt vmcnt(0)" ::: "memory"); }
    __builtin_amdgcn_s_barrier();
  }
#undef STG_A
#undef STG_B
#undef GATE

  // epilogue: row = m0+wm*64+mf*16+kgrp*4+r, col = n0+nf*64+wn*16+row16
#pragma unroll
  for (int mf = 0; mf < 4; mf++) {
    const int rowb = m0 + wm * 64 + mf * 16 + kgrp * 4;
#pragma unroll
    for (int nf = 0; nf < 2; nf++) {
      const int col = n0 + nf * 64 + wn * 16 + row16;
#pragma unroll
      for (int r = 0; r < 4; r++) {
        const float v = acc[mf][nf][r];
        const int rr2 = rowb + r;
        if constexpr (EPI == 0) {
          const int bbx = rr2 >> 10, s = rr2 & 1023;
          if (col < 1024) {
            const int hh = col >> 6, d = col & 63;
            qb[(((size_t)(bbx * NH_ + hh)) * S_ + s) * HD_ + d] = (bf16_t)(v * 0.125f);
          } else if (col < 2048) {
            const int c = col - 1024, hh = c >> 6, d = c & 63;
            kb[(((size_t)(bbx * NH_ + hh)) * S_ + s) * HD_ + d] = (bf16_t)v;
          } else {
            const int c = col - 2048, hh = c >> 6, d = c & 63;
            vtb[(((size_t)(bbx * NH_ + hh)) * HD_ + d) * S_ + s] = (bf16_t)v;
          }
        } else if constexpr (EPI == 1) {
          fout[(size_t)rr2 * N + col] += v;
        } else if constexpr (EPI == 2) {
          bout[(size_t)rr2 * N + col] = (bf16_t)fmaxf(v + bias[col], 0.0f);
        } else if constexpr (EPI == 3) {
          fout[(size_t)rr2 * N + col] += v + bias[col];
        } else {
          fout[(size_t)rr2 * N + col] = v + bias[col];
        }
      }
    }
  }
}

// ---------------------------------------------------------------------------
// Flash attention (causal), KVBLK=64, latency-pipelined (r9 structure) +
// MFMA-computed denominator (r11, neutral-verified): accL = P @ ones.
// ---------------------------------------------------------------------------
__global__ __launch_bounds__(256, 3) void attn_flash(const bf16_t* __restrict__ qg,
                                                     const bf16_t* __restrict__ kg,
                                                     const bf16_t* __restrict__ vtg,
                                                     bf16_t* __restrict__ aout) {
  const int nb = gridDim.x;
  const int logical = ((blockIdx.x & 7) * (nb >> 3)) + (blockIdx.x >> 3);
  const int qtile = logical & 15;
  const int bh    = logical >> 4;
  const int tid = threadIdx.x;
  const int wave = tid >> 6, lane = tid & 63;
  const int row16 = lane & 15, kgrp = lane >> 4;
  const int q0 = qtile * 64 + wave * 16;

  const bf16_t* qb = qg + (size_t)bh * S_ * HD_;
  const bf16_t* kb = kg + (size_t)bh * S_ * HD_;
  const bf16_t* vb = vtg + (size_t)bh * HD_ * S_;

  const bf16x8 qf0 = *(const bf16x8*)&qb[(size_t)(q0 + row16) * HD_ + kgrp * 8];
  const bf16x8 qf1 = *(const bf16x8*)&qb[(size_t)(q0 + row16) * HD_ + 32 + kgrp * 8];

  f32x4 accO[4] = {};
  f32x4 accL = {};
  float mrun[4] = {-1e30f, -1e30f, -1e30f, -1e30f};

  bf16x8 ones;
#pragma unroll
  for (int i = 0; i < 8; i++) ones[i] = (bf16_t)1.0f;

  __shared__ char sP[4][2048];
  char* const sw = &sP[wave][0];

  const int NTt = qtile + 1;

  bf16x8 kf[4][2];
#pragma unroll
  for (int q = 0; q < 4; q++) {
    kf[q][0] = *(const bf16x8*)&kb[(size_t)(q * 16 + row16) * HD_ + kgrp * 8];
    kf[q][1] = *(const bf16x8*)&kb[(size_t)(q * 16 + row16) * HD_ + 32 + kgrp * 8];
  }

  for (int t = 0; t < NTt; ++t) {
    const int k0 = t * 64;
    f32x4 sc[4];
#pragma unroll
    for (int q = 0; q < 4; q++) {
      f32x4 z = {};
      z = MFMA_BF16(qf0, kf[q][0], z);
      sc[q] = MFMA_BF16(qf1, kf[q][1], z);
    }
    bf16x8 vf[4][2];
#pragma unroll
    for (int d = 0; d < 4; d++) {
      vf[d][0] = *(const bf16x8*)&vb[(size_t)(d * 16 + row16) * S_ + k0 + kgrp * 8];
      vf[d][1] = *(const bf16x8*)&vb[(size_t)(d * 16 + row16) * S_ + k0 + 32 + kgrp * 8];
    }
    const bool diag = (k0 + 64 > q0);
    float p[4][4];
#pragma unroll
    for (int r = 0; r < 4; r++) {
      const int qglob = q0 + kgrp * 4 + r;
      float s0 = sc[0][r], s1 = sc[1][r], s2 = sc[2][r], s3 = sc[3][r];
      if (diag) {
        s0 = (k0 + row16 <= qglob) ? s0 : -1e30f;
        s1 = (k0 + 16 + row16 <= qglob) ? s1 : -1e30f;
        s2 = (k0 + 32 + row16 <= qglob) ? s2 : -1e30f;
        s3 = (k0 + 48 + row16 <= qglob) ? s3 : -1e30f;
      }
      float tmax = fmaxf(fmaxf(s0, s1), fmaxf(s2, s3));
#pragma unroll
      for (int msk = 1; msk < 16; msk <<= 1) tmax = fmaxf(tmax, __shfl_xor(tmax, msk, 64));
      const float mnew  = fmaxf(mrun[r], tmax);
      const float alpha = __expf(mrun[r] - mnew);
      mrun[r] = mnew;
      p[r][0] = __expf(s0 - mnew);
      p[r][1] = __expf(s1 - mnew);
      p[r][2] = __expf(s2 - mnew);
      p[r][3] = __expf(s3 - mnew);
      accL[r] *= alpha;
#pragma unroll
      for (int d = 0; d < 4; d++) accO[d][r] *= alpha;
    }
    if (t + 1 < NTt) {
      const int k0n = k0 + 64;
#pragma unroll
      for (int q = 0; q < 4; q++) {
        kf[q][0] = *(const bf16x8*)&kb[(size_t)(k0n + q * 16 + row16) * HD_ + kgrp * 8];
        kf[q][1] = *(const bf16x8*)&kb[(size_t)(k0n + q * 16 + row16) * HD_ + 32 + kgrp * 8];
      }
    }
#pragma unroll
    for (int r = 0; r < 4; r++) {
      const int prow = kgrp * 4 + r;
      const int px = (prow & 7) << 4;
#pragma unroll
      for (int q = 0; q < 4; q++) {
        *(bf16_t*)(sw + prow * 128 + (((q * 16 + row16) * 2) ^ px)) = (bf16_t)p[r][q];
      }
    }
    const int rx = (row16 & 7) << 4;
    const bf16x8 pf0 = *(const bf16x8*)(sw + row16 * 128 + ((kgrp * 16) ^ rx));
    const bf16x8 pf1 = *(const bf16x8*)(sw + row16 * 128 + ((64 + kgrp * 16) ^ rx));
    accL = MFMA_BF16(pf0, ones, accL);
    accL = MFMA_BF16(pf1, ones, accL);
#pragma unroll
    for (int d = 0; d < 4; d++) {
      accO[d] = MFMA_BF16(pf0, vf[d][0], accO[d]);
      accO[d] = MFMA_BF16(pf1, vf[d][1], accO[d]);
    }
  }

  float rinv[4];
#pragma unroll
  for (int r = 0; r < 4; r++) rinv[r] = 1.0f / accL[r];
  const int b = bh >> 4, hh = bh & 15;
#pragma unroll
  for (int d = 0; d < 4; d++)
#pragma unroll
    for (int r = 0; r < 4; r++) {
      const int tok = b * S_ + q0 + kgrp * 4 + r;
      aout[(size_t)tok * D_ + hh * HD_ + d * 16 + row16] = (bf16_t)(accO[d][r] * rinv[r]);
    }
}

// ---------------------------------------------------------------------------
// Launch
// ---------------------------------------------------------------------------
extern "C" void kernel_launch(void* const* d_in, const int* in_sizes, int n_in,
                              void* d_out, int out_size, void* d_ws, size_t ws_size,
                              hipStream_t stream) {
  const int*   x      = (const int*)d_in[0];
  const float* emb_W  = (const float*)d_in[1];
  const float* q_W    = (const float*)d_in[2];
  const float* k_W    = (const float*)d_in[3];
  const float* v_W    = (const float*)d_in[4];
  const float* o_W    = (const float*)d_in[5];
  const float* ln0_g  = (const float*)d_in[6];
  const float* ln0_b  = (const float*)d_in[7];
  const float* ln1_g  = (const float*)d_in[8];
  const float* ln1_b  = (const float*)d_in[9];
  const float* ffn_W1 = (const float*)d_in[10];
  const float* ffn_b1 = (const float*)d_in[11];
  const float* ffn_W2 = (const float*)d_in[12];
  const float* ffn_b2 = (const float*)d_in[13];
  const float* out_W  = (const float*)d_in[14];
  const float* out_b  = (const float*)d_in[15];
  float* out = (float*)d_out;

  char* p = (char*)d_ws;
  auto take = [&](size_t n) { char* r = p; p += (n + 255) & ~(size_t)255; return r; };
  float*  pe    = (float*)take((size_t)S_ * D_ * 4);
  float*  h     = (float*)take((size_t)TOK_ * D_ * 4);
  bf16_t* ain   = (bf16_t*)take((size_t)TOK_ * D_ * 2);
  bf16_t* attno = (bf16_t*)take((size_t)TOK_ * D_ * 2);
  bf16_t* qb    = (bf16_t*)take((size_t)B_ * NH_ * S_ * HD_ * 2);
  bf16_t* kb    = (bf16_t*)take((size_t)B_ * NH_ * S_ * HD_ * 2);
  bf16_t* vtb   = (bf16_t*)take((size_t)B_ * NH_ * S_ * HD_ * 2);
  bf16_t* ff    = (bf16_t*)take((size_t)TOK_ * HF_ * 2);
  bf16_t* qkvW  = (bf16_t*)take((size_t)3 * D_ * D_ * 2);
  bf16_t* oWb   = (bf16_t*)take((size_t)D_ * D_ * 2);
  bf16_t* W1b   = (bf16_t*)take((size_t)HF_ * D_ * 2);
  bf16_t* W2b   = (bf16_t*)take((size_t)D_ * HF_ * 2);
  bf16_t* outWb = (bf16_t*)take((size_t)V_ * D_ * 2);

  // --- weights -> bf16 ---
  cvt_f32_bf16<<<1024, 256, 0, stream>>>(q_W, qkvW, D_ * D_ / 4);
  cvt_f32_bf16<<<1024, 256, 0, stream>>>(k_W, qkvW + (size_t)D_ * D_, D_ * D_ / 4);
  cvt_f32_bf16<<<1024, 256, 0, stream>>>(v_W, qkvW + (size_t)2 * D_ * D_, D_ * D_ / 4);
  cvt_f32_bf16<<<1024, 256, 0, stream>>>(o_W, oWb, D_ * D_ / 4);
  cvt_f32_bf16<<<4096, 256, 0, stream>>>(ffn_W1, W1b, HF_ * D_ / 4);
  cvt_f32_bf16<<<4096, 256, 0, stream>>>(ffn_W2, W2b, D_ * HF_ / 4);
  cvt_f32_bf16<<<32000, 256, 0, stream>>>(out_W, outWb, V_ * D_ / 4);

  // --- embedding + PE ---
  pe_kernel<<<S_, 256, 0, stream>>>(pe);
  embed_kernel<<<TOK_ * D_ / 4 / 256, 256, 0, stream>>>(x, emb_W, pe, h);

  // --- transformer blocks (shared weights) ---
  for (int blk = 0; blk < 4; blk++) {
    ln_res_kernel<<<TOK_, 256, 0, stream>>>(h, ln0_g, ln0_b, ain);
    gemm_sq<0><<<32 * (3 * D_ / 128), 512, 0, stream>>>(
        ain, qkvW, 3 * D_, D_, 8, 8, nullptr, nullptr, nullptr, qb, kb, vtb);
    attn_flash<<<16 * B_ * NH_, 256, 0, stream>>>(qb, kb, vtb, attno);
    gemm_sq<1><<<32 * (D_ / 128), 512, 0, stream>>>(
        attno, oWb, D_, D_, D_ / 128, 32, h, nullptr, nullptr, nullptr, nullptr, nullptr);
    ln_res_kernel<<<TOK_, 256, 0, stream>>>(h, ln1_g, ln1_b, ain);
    gemm_sq<2><<<32 * (HF_ / 128), 512, 0, stream>>>(
        ain, W1b, HF_, D_, 8, 8, nullptr, ffn_b1, ff, nullptr, nullptr, nullptr);
    gemm_sq<3><<<32 * (D_ / 128), 512, 0, stream>>>(
        ff, W2b, D_, HF_, D_ / 128, 32, h, ffn_b2, nullptr, nullptr, nullptr, nullptr);
  }

  // --- final logits: supertile {10 N-tiles} x {4 M-tiles} (verified r13) ---
  cvt_f32_bf16<<<4096, 256, 0, stream>>>(h, ain, TOK_ * D_ / 4);
  gemm_sq<4><<<32 * (V_ / 128), 512, 0, stream>>>(
      ain, outWb, V_, D_, 10, 4, out, out_b, nullptr, nullptr, nullptr, nullptr);
}

// Round 17
// 1385.309 us; speedup vs baseline: 1.1451x; 1.0632x over previous
//
#include <hip/hip_runtime.h>
#include <hip/hip_bf16.h>
#include <math.h>

// ---------------------------------------------------------------------------
// Types
// ---------------------------------------------------------------------------
typedef __bf16 bf16_t;
typedef __bf16 bf16x8 __attribute__((ext_vector_type(8)));
typedef __bf16 bf16x4 __attribute__((ext_vector_type(4)));
typedef float  f32x4  __attribute__((ext_vector_type(4)));

#define MFMA_BF16(a, b, c) __builtin_amdgcn_mfma_f32_16x16x32_bf16((a), (b), (c), 0, 0, 0)

typedef const void __attribute__((address_space(1)))* gas_ptr;
typedef void       __attribute__((address_space(3)))* las_ptr;

__device__ __forceinline__ void gload_lds16(const void* g, void* l) {
  // global -> LDS direct, 16B per lane. LDS dest is wave-uniform base + lane*16.
  __builtin_amdgcn_global_load_lds((gas_ptr)g, (las_ptr)l, 16, 0, 0);
}

// ---------------------------------------------------------------------------
// Model constants
// ---------------------------------------------------------------------------
static constexpr int B_ = 4, S_ = 1024, D_ = 1024, HF_ = 4096, V_ = 32000;
static constexpr int NH_ = 16, HD_ = 64;
static constexpr int TOK_ = B_ * S_;  // 4096

// ---------------------------------------------------------------------------
// fp32 -> bf16 conversion (vectorized x4)
// ---------------------------------------------------------------------------
__global__ __launch_bounds__(256) void cvt_f32_bf16(const float* __restrict__ in,
                                                    bf16_t* __restrict__ out, int n4) {
  int i = blockIdx.x * 256 + threadIdx.x;
  if (i < n4) {
    float4 v = ((const float4*)in)[i];
    bf16x4 o;
    o[0] = (bf16_t)v.x; o[1] = (bf16_t)v.y; o[2] = (bf16_t)v.z; o[3] = (bf16_t)v.w;
    ((bf16x4*)out)[i] = o;
  }
}

// ---------------------------------------------------------------------------
// Sinusoidal positional encoding table
// ---------------------------------------------------------------------------
__global__ __launch_bounds__(256) void pe_kernel(float* __restrict__ pe) {
  const int s = blockIdx.x;
  for (int i = threadIdx.x; i < D_ / 2; i += 256) {
    float div = expf((2.0f * (float)i) * (-9.210340371976184f / (float)D_)); // ln(10000)
    float a = (float)s * div;
    pe[(size_t)s * D_ + 2 * i]     = sinf(a);
    pe[(size_t)s * D_ + 2 * i + 1] = cosf(a);
  }
}

// ---------------------------------------------------------------------------
// Embedding: h[t][d] = emb_W[x[t]][d] * 32 + pe[t % S][d]
// ---------------------------------------------------------------------------
__global__ __launch_bounds__(256) void embed_kernel(const int* __restrict__ x,
                                                    const float* __restrict__ embW,
                                                    const float* __restrict__ pe,
                                                    float* __restrict__ h) {
  int i = blockIdx.x * 256 + threadIdx.x;
  int token = i >> 8;
  int c4 = i & 255;
  int idx = x[token];
  float4 e = ((const float4*)(embW + (size_t)idx * D_))[c4];
  float4 p = ((const float4*)(pe + (size_t)(token & (S_ - 1)) * D_))[c4];
  float4 o;
  o.x = e.x * 32.0f + p.x; o.y = e.y * 32.0f + p.y;
  o.z = e.z * 32.0f + p.z; o.w = e.w * 32.0f + p.w;
  ((float4*)(h + (size_t)token * D_))[c4] = o;
}

// ---------------------------------------------------------------------------
// a_in = h + LayerNorm(h)*g + b   -> bf16
// ---------------------------------------------------------------------------
__global__ __launch_bounds__(256) void ln_res_kernel(const float* __restrict__ h,
                                                     const float* __restrict__ gamma,
                                                     const float* __restrict__ beta,
                                                     bf16_t* __restrict__ out) {
  const int row = blockIdx.x;
  const int tid = threadIdx.x;
  const float4 v = ((const float4*)(h + (size_t)row * D_))[tid];
  float s  = v.x + v.y + v.z + v.w;
  float s2 = v.x * v.x + v.y * v.y + v.z * v.z + v.w * v.w;
#pragma unroll
  for (int m = 1; m < 64; m <<= 1) {
    s  += __shfl_xor(s, m, 64);
    s2 += __shfl_xor(s2, m, 64);
  }
  __shared__ float red[2][4];
  const int wave = tid >> 6, lane = tid & 63;
  if (lane == 0) { red[0][wave] = s; red[1][wave] = s2; }
  __syncthreads();
  s  = red[0][0] + red[0][1] + red[0][2] + red[0][3];
  s2 = red[1][0] + red[1][1] + red[1][2] + red[1][3];
  const float mu   = s * (1.0f / D_);
  const float rstd = rsqrtf(s2 * (1.0f / D_) - mu * mu + 1e-5f);
  const float4 g4 = ((const float4*)gamma)[tid];
  const float4 b4 = ((const float4*)beta)[tid];
  bf16x4 o;
  o[0] = (bf16_t)(v.x + (v.x - mu) * rstd * g4.x + b4.x);
  o[1] = (bf16_t)(v.y + (v.y - mu) * rstd * g4.y + b4.y);
  o[2] = (bf16_t)(v.z + (v.z - mu) * rstd * g4.z + b4.z);
  o[3] = (bf16_t)(v.w + (v.w - mu) * rstd * g4.w + b4.w);
  ((bf16x4*)(out + (size_t)row * D_))[tid] = o;
}

// ---------------------------------------------------------------------------
// gemm_sq: 128x128 tile, BK=64, 2 phases/K-tile, 2 blocks/CU (verified r10).
// C[4096,N] = A[4096,K] @ W[N,K]^T. 8 waves (2M x 4N); per-wave 64x32.
// LDS 2 x 32 KB dbuf; launch_bounds(512,4) => 2 blocks/CU; sibling block
// covers barrier/drain/epilogue stalls. Counted vmcnt(2), never 0 mid-loop.
// Swizzle: 128B rows, byte ^ ((row&7)<<4), involution. XCD swizzle +
// 2-D SUPERTILE ordering (verified r13/r16). Sizing rule: live set =
// mch*256KB (A) + band_n*256KB (B) <= 4MB with band_n*mch ~= 64.
//   logits: (10,4); QKV/FFN1 (K=1024): (8,8); N=1024 shapes: identity decode.
// Epilogues: 0 QKV-scatter, 1 fout+=v, 2 relu(v+bias)->bf16, 3 fout+=v+bias,
//            4 fout = v + bias (pure store, logits).
// ---------------------------------------------------------------------------
template <int EPI>
__global__ __launch_bounds__(512, 4) void gemm_sq(
    const bf16_t* __restrict__ A, const bf16_t* __restrict__ W, int N, int K,
    int band_n, int mch,
    float* __restrict__ fout, const float* __restrict__ bias, bf16_t* __restrict__ bout,
    bf16_t* __restrict__ qb, bf16_t* __restrict__ kb, bf16_t* __restrict__ vtb) {
  __shared__ char lds[2][32768];

  const int tid = threadIdx.x;
  const int wave = tid >> 6, lane = tid & 63;
  const int row16 = lane & 15, kgrp = lane >> 4;
  const int wm = wave >> 2, wn = wave & 3;  // 2M x 4N

  const int nb = gridDim.x;  // multiple of 8
  const int logical = (blockIdx.x & 7) * (nb >> 3) + (blockIdx.x >> 3);
  // supertile decode: {band of band_n N-tiles} x {chunk of mch M-tiles},
  // M fastest within supertile; chunks inner, bands outer. (M = 32 tiles)
  const int st = band_n * mch;
  const int stid = logical / st;
  const int rr = logical - stid * st;
  const int nMch = 32 / mch;
  const int band = stid / nMch;
  const int mchid = stid - band * nMch;
  const int m0 = (mchid * mch + (rr % mch)) << 7;
  const int n0 = (band * band_n + rr / mch) << 7;
  const size_t K2 = (size_t)K * 2;

  const int lr = lane >> 3;
  const int swz = ((lane & 7) * 16) ^ (lr << 4);
  const char* gA = (const char*)A + (size_t)(m0 + wave * 8 + lr) * K2 + swz;
  const char* gB = (const char*)W + (size_t)(n0 + wave * 8 + lr) * K2 + swz;
  char* const ldsc = &lds[0][0];
  const int dW = wave * 1024;

#define STG_A(v)                                                  \
  { char* d_ = ldsc + (((v) & 1) << 15) + dW;                     \
    const char* g_ = gA + (size_t)(v) * 128;                      \
    gload_lds16(g_, d_); gload_lds16(g_ + 64 * K2, d_ + 8192); }
#define STG_B(v)                                                  \
  { char* d_ = ldsc + (((v) & 1) << 15) + 16384 + dW;             \
    const char* g_ = gB + (size_t)(v) * 128;                      \
    gload_lds16(g_, d_); gload_lds16(g_ + 64 * K2, d_ + 8192); }

  const int colx0 = (kgrp * 16) ^ ((row16 & 7) << 4);
  const int colx1 = (64 + kgrp * 16) ^ ((row16 & 7) << 4);
  int aoff[4], boff[2];
#pragma unroll
  for (int mf = 0; mf < 4; mf++) aoff[mf] = (wm * 64 + mf * 16 + row16) * 128;
#pragma unroll
  for (int nf = 0; nf < 2; nf++) boff[nf] = 16384 + (nf * 64 + wn * 16 + row16) * 128;

#define GATE()                                        \
  __builtin_amdgcn_s_barrier();                       \
  asm volatile("s_waitcnt lgkmcnt(0)" ::: "memory");  \
  __builtin_amdgcn_sched_barrier(0);

  f32x4 acc[4][2] = {};
  bf16x8 af[4][2], bfr[2];
  const int NT = K >> 6;

  STG_A(0); STG_B(0); STG_A(1);
  asm volatile("s_waitcnt vmcnt(2)" ::: "memory");  // A(0), B(0) landed
  __builtin_amdgcn_s_barrier();

  for (int t = 0; t < NT; ++t) {
    const char* bufp = ldsc + ((t & 1) << 15);
    // ---- P0: all m x n01 ----
#pragma unroll
    for (int mf = 0; mf < 4; mf++) {
      af[mf][0] = *(const bf16x8*)(bufp + aoff[mf] + colx0);
      af[mf][1] = *(const bf16x8*)(bufp + aoff[mf] + colx1);
    }
    bfr[0] = *(const bf16x8*)(bufp + boff[0] + colx0);
    bfr[1] = *(const bf16x8*)(bufp + boff[0] + colx1);
    if (t + 1 < NT) STG_B(t + 1);
    GATE();
    __builtin_amdgcn_s_setprio(1);
#pragma unroll
    for (int mf = 0; mf < 4; mf++) {
      acc[mf][0] = MFMA_BF16(af[mf][0], bfr[0], acc[mf][0]);
      acc[mf][0] = MFMA_BF16(af[mf][1], bfr[1], acc[mf][0]);
    }
    __builtin_amdgcn_s_setprio(0);
    __builtin_amdgcn_s_barrier();
    // ---- P1: all m x n23 ----
    bfr[0] = *(const bf16x8*)(bufp + boff[1] + colx0);
    bfr[1] = *(const bf16x8*)(bufp + boff[1] + colx1);
    if (t + 2 < NT) STG_A(t + 2);
    GATE();
    __builtin_amdgcn_s_setprio(1);
#pragma unroll
    for (int mf = 0; mf < 4; mf++) {
      acc[mf][1] = MFMA_BF16(af[mf][0], bfr[0], acc[mf][1]);
      acc[mf][1] = MFMA_BF16(af[mf][1], bfr[1], acc[mf][1]);
    }
    __builtin_amdgcn_s_setprio(0);
    if (t + 2 < NT)      { asm volatile("s_waitcnt vmcnt(2)" ::: "memory"); }
    else if (t + 1 < NT) { asm volatile("s_waitcnt vmcnt(0)" ::: "memory"); }
    __builtin_amdgcn_s_barrier();
  }
#undef STG_A
#undef STG_B
#undef GATE

  // epilogue: row = m0+wm*64+mf*16+kgrp*4+r, col = n0+nf*64+wn*16+row16
#pragma unroll
  for (int mf = 0; mf < 4; mf++) {
    const int rowb = m0 + wm * 64 + mf * 16 + kgrp * 4;
#pragma unroll
    for (int nf = 0; nf < 2; nf++) {
      const int col = n0 + nf * 64 + wn * 16 + row16;
#pragma unroll
      for (int r = 0; r < 4; r++) {
        const float v = acc[mf][nf][r];
        const int rr2 = rowb + r;
        if constexpr (EPI == 0) {
          const int bbx = rr2 >> 10, s = rr2 & 1023;
          if (col < 1024) {
            const int hh = col >> 6, d = col & 63;
            qb[(((size_t)(bbx * NH_ + hh)) * S_ + s) * HD_ + d] = (bf16_t)(v * 0.125f);
          } else if (col < 2048) {
            const int c = col - 1024, hh = c >> 6, d = c & 63;
            kb[(((size_t)(bbx * NH_ + hh)) * S_ + s) * HD_ + d] = (bf16_t)v;
          } else {
            const int c = col - 2048, hh = c >> 6, d = c & 63;
            vtb[(((size_t)(bbx * NH_ + hh)) * HD_ + d) * S_ + s] = (bf16_t)v;
          }
        } else if constexpr (EPI == 1) {
          fout[(size_t)rr2 * N + col] += v;
        } else if constexpr (EPI == 2) {
          bout[(size_t)rr2 * N + col] = (bf16_t)fmaxf(v + bias[col], 0.0f);
        } else if constexpr (EPI == 3) {
          fout[(size_t)rr2 * N + col] += v + bias[col];
        } else {
          fout[(size_t)rr2 * N + col] = v + bias[col];
        }
      }
    }
  }
}

// ---------------------------------------------------------------------------
// Flash attention (causal), KVBLK=64, latency-pipelined (r9 structure) +
// MFMA denominator (r11) + ANTITHETIC PAIRING (r17): each block processes
// qtiles {p, 15-p} -> exactly 17 work-units per block (work ~ qtile+1 was a
// 16x imbalance). Grid 512 = 2 blocks/CU, all resident; the XCD swizzle maps
// all 8 pair-blocks of one head to one XCD (per-head K/V L2 locality).
// ---------------------------------------------------------------------------
__global__ __launch_bounds__(256, 3) void attn_flash(const bf16_t* __restrict__ qg,
                                                     const bf16_t* __restrict__ kg,
                                                     const bf16_t* __restrict__ vtg,
                                                     bf16_t* __restrict__ aout) {
  const int nb = gridDim.x;  // 512
  const int logical = ((blockIdx.x & 7) * (nb >> 3)) + (blockIdx.x >> 3);
  const int pair = logical & 7;   // 0..7
  const int bh   = logical >> 3;  // 0..63
  const int tid = threadIdx.x;
  const int wave = tid >> 6, lane = tid & 63;
  const int row16 = lane & 15, kgrp = lane >> 4;

  const bf16_t* qb = qg + (size_t)bh * S_ * HD_;
  const bf16_t* kb = kg + (size_t)bh * S_ * HD_;
  const bf16_t* vb = vtg + (size_t)bh * HD_ * S_;

  bf16x8 ones;
#pragma unroll
  for (int i = 0; i < 8; i++) ones[i] = (bf16_t)1.0f;

  __shared__ char sP[4][2048];
  char* const sw = &sP[wave][0];
  const int b = bh >> 4, hh = bh & 15;

  for (int it = 0; it < 2; ++it) {
    const int qtile = it ? (15 - pair) : pair;
    const int q0 = qtile * 64 + wave * 16;

    const bf16x8 qf0 = *(const bf16x8*)&qb[(size_t)(q0 + row16) * HD_ + kgrp * 8];
    const bf16x8 qf1 = *(const bf16x8*)&qb[(size_t)(q0 + row16) * HD_ + 32 + kgrp * 8];

    f32x4 accO[4] = {};
    f32x4 accL = {};
    float mrun[4] = {-1e30f, -1e30f, -1e30f, -1e30f};

    const int NTt = qtile + 1;

    bf16x8 kf[4][2];
#pragma unroll
    for (int q = 0; q < 4; q++) {
      kf[q][0] = *(const bf16x8*)&kb[(size_t)(q * 16 + row16) * HD_ + kgrp * 8];
      kf[q][1] = *(const bf16x8*)&kb[(size_t)(q * 16 + row16) * HD_ + 32 + kgrp * 8];
    }

    for (int t = 0; t < NTt; ++t) {
      const int k0 = t * 64;
      f32x4 sc[4];
#pragma unroll
      for (int q = 0; q < 4; q++) {
        f32x4 z = {};
        z = MFMA_BF16(qf0, kf[q][0], z);
        sc[q] = MFMA_BF16(qf1, kf[q][1], z);
      }
      bf16x8 vf[4][2];
#pragma unroll
      for (int d = 0; d < 4; d++) {
        vf[d][0] = *(const bf16x8*)&vb[(size_t)(d * 16 + row16) * S_ + k0 + kgrp * 8];
        vf[d][1] = *(const bf16x8*)&vb[(size_t)(d * 16 + row16) * S_ + k0 + 32 + kgrp * 8];
      }
      const bool diag = (k0 + 64 > q0);
      float p[4][4];
#pragma unroll
      for (int r = 0; r < 4; r++) {
        const int qglob = q0 + kgrp * 4 + r;
        float s0 = sc[0][r], s1 = sc[1][r], s2 = sc[2][r], s3 = sc[3][r];
        if (diag) {
          s0 = (k0 + row16 <= qglob) ? s0 : -1e30f;
          s1 = (k0 + 16 + row16 <= qglob) ? s1 : -1e30f;
          s2 = (k0 + 32 + row16 <= qglob) ? s2 : -1e30f;
          s3 = (k0 + 48 + row16 <= qglob) ? s3 : -1e30f;
        }
        float tmax = fmaxf(fmaxf(s0, s1), fmaxf(s2, s3));
#pragma unroll
        for (int msk = 1; msk < 16; msk <<= 1) tmax = fmaxf(tmax, __shfl_xor(tmax, msk, 64));
        const float mnew  = fmaxf(mrun[r], tmax);
        const float alpha = __expf(mrun[r] - mnew);
        mrun[r] = mnew;
        p[r][0] = __expf(s0 - mnew);
        p[r][1] = __expf(s1 - mnew);
        p[r][2] = __expf(s2 - mnew);
        p[r][3] = __expf(s3 - mnew);
        accL[r] *= alpha;
#pragma unroll
        for (int d = 0; d < 4; d++) accO[d][r] *= alpha;
      }
      if (t + 1 < NTt) {
        const int k0n = k0 + 64;
#pragma unroll
        for (int q = 0; q < 4; q++) {
          kf[q][0] = *(const bf16x8*)&kb[(size_t)(k0n + q * 16 + row16) * HD_ + kgrp * 8];
          kf[q][1] = *(const bf16x8*)&kb[(size_t)(k0n + q * 16 + row16) * HD_ + 32 + kgrp * 8];
        }
      }
#pragma unroll
      for (int r = 0; r < 4; r++) {
        const int prow = kgrp * 4 + r;
        const int px = (prow & 7) << 4;
#pragma unroll
        for (int q = 0; q < 4; q++) {
          *(bf16_t*)(sw + prow * 128 + (((q * 16 + row16) * 2) ^ px)) = (bf16_t)p[r][q];
        }
      }
      const int rx = (row16 & 7) << 4;
      const bf16x8 pf0 = *(const bf16x8*)(sw + row16 * 128 + ((kgrp * 16) ^ rx));
      const bf16x8 pf1 = *(const bf16x8*)(sw + row16 * 128 + ((64 + kgrp * 16) ^ rx));
      accL = MFMA_BF16(pf0, ones, accL);
      accL = MFMA_BF16(pf1, ones, accL);
#pragma unroll
      for (int d = 0; d < 4; d++) {
        accO[d] = MFMA_BF16(pf0, vf[d][0], accO[d]);
        accO[d] = MFMA_BF16(pf1, vf[d][1], accO[d]);
      }
    }

    float rinv[4];
#pragma unroll
    for (int r = 0; r < 4; r++) rinv[r] = 1.0f / accL[r];
#pragma unroll
    for (int d = 0; d < 4; d++)
#pragma unroll
      for (int r = 0; r < 4; r++) {
        const int tok = b * S_ + q0 + kgrp * 4 + r;
        aout[(size_t)tok * D_ + hh * HD_ + d * 16 + row16] = (bf16_t)(accO[d][r] * rinv[r]);
      }
  }
}

// ---------------------------------------------------------------------------
// Launch
// ---------------------------------------------------------------------------
extern "C" void kernel_launch(void* const* d_in, const int* in_sizes, int n_in,
                              void* d_out, int out_size, void* d_ws, size_t ws_size,
                              hipStream_t stream) {
  const int*   x      = (const int*)d_in[0];
  const float* emb_W  = (const float*)d_in[1];
  const float* q_W    = (const float*)d_in[2];
  const float* k_W    = (const float*)d_in[3];
  const float* v_W    = (const float*)d_in[4];
  const float* o_W    = (const float*)d_in[5];
  const float* ln0_g  = (const float*)d_in[6];
  const float* ln0_b  = (const float*)d_in[7];
  const float* ln1_g  = (const float*)d_in[8];
  const float* ln1_b  = (const float*)d_in[9];
  const float* ffn_W1 = (const float*)d_in[10];
  const float* ffn_b1 = (const float*)d_in[11];
  const float* ffn_W2 = (const float*)d_in[12];
  const float* ffn_b2 = (const float*)d_in[13];
  const float* out_W  = (const float*)d_in[14];
  const float* out_b  = (const float*)d_in[15];
  float* out = (float*)d_out;

  char* p = (char*)d_ws;
  auto take = [&](size_t n) { char* r = p; p += (n + 255) & ~(size_t)255; return r; };
  float*  pe    = (float*)take((size_t)S_ * D_ * 4);
  float*  h     = (float*)take((size_t)TOK_ * D_ * 4);
  bf16_t* ain   = (bf16_t*)take((size_t)TOK_ * D_ * 2);
  bf16_t* attno = (bf16_t*)take((size_t)TOK_ * D_ * 2);
  bf16_t* qb    = (bf16_t*)take((size_t)B_ * NH_ * S_ * HD_ * 2);
  bf16_t* kb    = (bf16_t*)take((size_t)B_ * NH_ * S_ * HD_ * 2);
  bf16_t* vtb   = (bf16_t*)take((size_t)B_ * NH_ * S_ * HD_ * 2);
  bf16_t* ff    = (bf16_t*)take((size_t)TOK_ * HF_ * 2);
  bf16_t* qkvW  = (bf16_t*)take((size_t)3 * D_ * D_ * 2);
  bf16_t* oWb   = (bf16_t*)take((size_t)D_ * D_ * 2);
  bf16_t* W1b   = (bf16_t*)take((size_t)HF_ * D_ * 2);
  bf16_t* W2b   = (bf16_t*)take((size_t)D_ * HF_ * 2);
  bf16_t* outWb = (bf16_t*)take((size_t)V_ * D_ * 2);

  // --- weights -> bf16 ---
  cvt_f32_bf16<<<1024, 256, 0, stream>>>(q_W, qkvW, D_ * D_ / 4);
  cvt_f32_bf16<<<1024, 256, 0, stream>>>(k_W, qkvW + (size_t)D_ * D_, D_ * D_ / 4);
  cvt_f32_bf16<<<1024, 256, 0, stream>>>(v_W, qkvW + (size_t)2 * D_ * D_, D_ * D_ / 4);
  cvt_f32_bf16<<<1024, 256, 0, stream>>>(o_W, oWb, D_ * D_ / 4);
  cvt_f32_bf16<<<4096, 256, 0, stream>>>(ffn_W1, W1b, HF_ * D_ / 4);
  cvt_f32_bf16<<<4096, 256, 0, stream>>>(ffn_W2, W2b, D_ * HF_ / 4);
  cvt_f32_bf16<<<32000, 256, 0, stream>>>(out_W, outWb, V_ * D_ / 4);

  // --- embedding + PE ---
  pe_kernel<<<S_, 256, 0, stream>>>(pe);
  embed_kernel<<<TOK_ * D_ / 4 / 256, 256, 0, stream>>>(x, emb_W, pe, h);

  // --- transformer blocks (shared weights) ---
  for (int blk = 0; blk < 4; blk++) {
    ln_res_kernel<<<TOK_, 256, 0, stream>>>(h, ln0_g, ln0_b, ain);
    gemm_sq<0><<<32 * (3 * D_ / 128), 512, 0, stream>>>(
        ain, qkvW, 3 * D_, D_, 8, 8, nullptr, nullptr, nullptr, qb, kb, vtb);
    attn_flash<<<8 * B_ * NH_, 256, 0, stream>>>(qb, kb, vtb, attno);
    gemm_sq<1><<<32 * (D_ / 128), 512, 0, stream>>>(
        attno, oWb, D_, D_, D_ / 128, 32, h, nullptr, nullptr, nullptr, nullptr, nullptr);
    ln_res_kernel<<<TOK_, 256, 0, stream>>>(h, ln1_g, ln1_b, ain);
    gemm_sq<2><<<32 * (HF_ / 128), 512, 0, stream>>>(
        ain, W1b, HF_, D_, 8, 8, nullptr, ffn_b1, ff, nullptr, nullptr, nullptr);
    gemm_sq<3><<<32 * (D_ / 128), 512, 0, stream>>>(
        ff, W2b, D_, HF_, D_ / 128, 32, h, ffn_b2, nullptr, nullptr, nullptr, nullptr);
  }

  // --- final logits: supertile {10 N-tiles} x {4 M-tiles} (verified r13) ---
  cvt_f32_bf16<<<4096, 256, 0, stream>>>(h, ain, TOK_ * D_ / 4);
  gemm_sq<4><<<32 * (V_ / 128), 512, 0, stream>>>(
      ain, outWb, V_, D_, 10, 4, out, out_b, nullptr, nullptr, nullptr, nullptr);
}

// Round 19
// 1380.456 us; speedup vs baseline: 1.1492x; 1.0035x over previous
//
#include <hip/hip_runtime.h>
#include <hip/hip_bf16.h>
#include <math.h>

// ---------------------------------------------------------------------------
// Types
// ---------------------------------------------------------------------------
typedef __bf16 bf16_t;
typedef __bf16 bf16x8 __attribute__((ext_vector_type(8)));
typedef __bf16 bf16x4 __attribute__((ext_vector_type(4)));
typedef float  f32x4  __attribute__((ext_vector_type(4)));

#define MFMA_BF16(a, b, c) __builtin_amdgcn_mfma_f32_16x16x32_bf16((a), (b), (c), 0, 0, 0)

typedef const void __attribute__((address_space(1)))* gas_ptr;
typedef void       __attribute__((address_space(3)))* las_ptr;

__device__ __forceinline__ void gload_lds16(const void* g, void* l) {
  // global -> LDS direct, 16B per lane. LDS dest is wave-uniform base + lane*16.
  __builtin_amdgcn_global_load_lds((gas_ptr)g, (las_ptr)l, 16, 0, 0);
}

// ---------------------------------------------------------------------------
// Model constants
// ---------------------------------------------------------------------------
static constexpr int B_ = 4, S_ = 1024, D_ = 1024, HF_ = 4096, V_ = 32000;
static constexpr int NH_ = 16, HD_ = 64;
static constexpr int TOK_ = B_ * S_;  // 4096

// ---------------------------------------------------------------------------
// fp32 -> bf16 conversion (vectorized x4)
// ---------------------------------------------------------------------------
__global__ __launch_bounds__(256) void cvt_f32_bf16(const float* __restrict__ in,
                                                    bf16_t* __restrict__ out, int n4) {
  int i = blockIdx.x * 256 + threadIdx.x;
  if (i < n4) {
    float4 v = ((const float4*)in)[i];
    bf16x4 o;
    o[0] = (bf16_t)v.x; o[1] = (bf16_t)v.y; o[2] = (bf16_t)v.z; o[3] = (bf16_t)v.w;
    ((bf16x4*)out)[i] = o;
  }
}

// ---------------------------------------------------------------------------
// Sinusoidal positional encoding table
// ---------------------------------------------------------------------------
__global__ __launch_bounds__(256) void pe_kernel(float* __restrict__ pe) {
  const int s = blockIdx.x;
  for (int i = threadIdx.x; i < D_ / 2; i += 256) {
    float div = expf((2.0f * (float)i) * (-9.210340371976184f / (float)D_)); // ln(10000)
    float a = (float)s * div;
    pe[(size_t)s * D_ + 2 * i]     = sinf(a);
    pe[(size_t)s * D_ + 2 * i + 1] = cosf(a);
  }
}

// ---------------------------------------------------------------------------
// Embedding: h[t][d] = emb_W[x[t]][d] * 32 + pe[t % S][d]
// ---------------------------------------------------------------------------
__global__ __launch_bounds__(256) void embed_kernel(const int* __restrict__ x,
                                                    const float* __restrict__ embW,
                                                    const float* __restrict__ pe,
                                                    float* __restrict__ h) {
  int i = blockIdx.x * 256 + threadIdx.x;
  int token = i >> 8;
  int c4 = i & 255;
  int idx = x[token];
  float4 e = ((const float4*)(embW + (size_t)idx * D_))[c4];
  float4 p = ((const float4*)(pe + (size_t)(token & (S_ - 1)) * D_))[c4];
  float4 o;
  o.x = e.x * 32.0f + p.x; o.y = e.y * 32.0f + p.y;
  o.z = e.z * 32.0f + p.z; o.w = e.w * 32.0f + p.w;
  ((float4*)(h + (size_t)token * D_))[c4] = o;
}

// ---------------------------------------------------------------------------
// a_in = h + LayerNorm(h)*g + b   -> bf16
// ---------------------------------------------------------------------------
__global__ __launch_bounds__(256) void ln_res_kernel(const float* __restrict__ h,
                                                     const float* __restrict__ gamma,
                                                     const float* __restrict__ beta,
                                                     bf16_t* __restrict__ out) {
  const int row = blockIdx.x;
  const int tid = threadIdx.x;
  const float4 v = ((const float4*)(h + (size_t)row * D_))[tid];
  float s  = v.x + v.y + v.z + v.w;
  float s2 = v.x * v.x + v.y * v.y + v.z * v.z + v.w * v.w;
#pragma unroll
  for (int m = 1; m < 64; m <<= 1) {
    s  += __shfl_xor(s, m, 64);
    s2 += __shfl_xor(s2, m, 64);
  }
  __shared__ float red[2][4];
  const int wave = tid >> 6, lane = tid & 63;
  if (lane == 0) { red[0][wave] = s; red[1][wave] = s2; }
  __syncthreads();
  s  = red[0][0] + red[0][1] + red[0][2] + red[0][3];
  s2 = red[1][0] + red[1][1] + red[1][2] + red[1][3];
  const float mu   = s * (1.0f / D_);
  const float rstd = rsqrtf(s2 * (1.0f / D_) - mu * mu + 1e-5f);
  const float4 g4 = ((const float4*)gamma)[tid];
  const float4 b4 = ((const float4*)beta)[tid];
  bf16x4 o;
  o[0] = (bf16_t)(v.x + (v.x - mu) * rstd * g4.x + b4.x);
  o[1] = (bf16_t)(v.y + (v.y - mu) * rstd * g4.y + b4.y);
  o[2] = (bf16_t)(v.z + (v.z - mu) * rstd * g4.z + b4.z);
  o[3] = (bf16_t)(v.w + (v.w - mu) * rstd * g4.w + b4.w);
  ((bf16x4*)(out + (size_t)row * D_))[tid] = o;
}

// ---------------------------------------------------------------------------
// gemm_sq: 128x128 tile, BK=64, 2 phases/K-tile, 2 blocks/CU (verified r10).
// C[4096,N] = A[4096,K] @ W[N,K]^T. 8 waves (2M x 4N); per-wave 64x32.
// LDS 2 x 32 KB dbuf; launch_bounds(512,4) => 2 blocks/CU; sibling block
// covers barrier/drain/epilogue stalls. Counted vmcnt(2), never 0 mid-loop.
// Swizzle: 128B rows, byte ^ ((row&7)<<4), involution. XCD swizzle +
// 2-D SUPERTILE ordering (verified r13/r16). Sizing rule: live set =
// mch*256KB (A) + band_n*256KB (B) <= 4MB with band_n*mch ~= 64.
//   logits: (10,4); QKV/FFN1/O-proj: (8,8); FFN2: identity (A L3-resident).
// Epilogues: 0 QKV-scatter, 1 fout+=v, 2 relu(v+bias)->bf16, 3 fout+=v+bias,
//            4 fout = v + bias (pure store, logits).
// ---------------------------------------------------------------------------
template <int EPI>
__global__ __launch_bounds__(512, 4) void gemm_sq(
    const bf16_t* __restrict__ A, const bf16_t* __restrict__ W, int N, int K,
    int band_n, int mch,
    float* __restrict__ fout, const float* __restrict__ bias, bf16_t* __restrict__ bout,
    bf16_t* __restrict__ qb, bf16_t* __restrict__ kb, bf16_t* __restrict__ vtb) {
  __shared__ char lds[2][32768];

  const int tid = threadIdx.x;
  const int wave = tid >> 6, lane = tid & 63;
  const int row16 = lane & 15, kgrp = lane >> 4;
  const int wm = wave >> 2, wn = wave & 3;  // 2M x 4N

  const int nb = gridDim.x;  // multiple of 8
  const int logical = (blockIdx.x & 7) * (nb >> 3) + (blockIdx.x >> 3);
  // supertile decode: {band of band_n N-tiles} x {chunk of mch M-tiles},
  // M fastest within supertile; chunks inner, bands outer. (M = 32 tiles)
  const int st = band_n * mch;
  const int stid = logical / st;
  const int rr = logical - stid * st;
  const int nMch = 32 / mch;
  const int band = stid / nMch;
  const int mchid = stid - band * nMch;
  const int m0 = (mchid * mch + (rr % mch)) << 7;
  const int n0 = (band * band_n + rr / mch) << 7;
  const size_t K2 = (size_t)K * 2;

  const int lr = lane >> 3;
  const int swz = ((lane & 7) * 16) ^ (lr << 4);
  const char* gA = (const char*)A + (size_t)(m0 + wave * 8 + lr) * K2 + swz;
  const char* gB = (const char*)W + (size_t)(n0 + wave * 8 + lr) * K2 + swz;
  char* const ldsc = &lds[0][0];
  const int dW = wave * 1024;

#define STG_A(v)                                                  \
  { char* d_ = ldsc + (((v) & 1) << 15) + dW;                     \
    const char* g_ = gA + (size_t)(v) * 128;                      \
    gload_lds16(g_, d_); gload_lds16(g_ + 64 * K2, d_ + 8192); }
#define STG_B(v)                                                  \
  { char* d_ = ldsc + (((v) & 1) << 15) + 16384 + dW;             \
    const char* g_ = gB + (size_t)(v) * 128;                      \
    gload_lds16(g_, d_); gload_lds16(g_ + 64 * K2, d_ + 8192); }

  const int colx0 = (kgrp * 16) ^ ((row16 & 7) << 4);
  const int colx1 = (64 + kgrp * 16) ^ ((row16 & 7) << 4);
  int aoff[4], boff[2];
#pragma unroll
  for (int mf = 0; mf < 4; mf++) aoff[mf] = (wm * 64 + mf * 16 + row16) * 128;
#pragma unroll
  for (int nf = 0; nf < 2; nf++) boff[nf] = 16384 + (nf * 64 + wn * 16 + row16) * 128;

#define GATE()                                        \
  __builtin_amdgcn_s_barrier();                       \
  asm volatile("s_waitcnt lgkmcnt(0)" ::: "memory");  \
  __builtin_amdgcn_sched_barrier(0);

  f32x4 acc[4][2] = {};
  bf16x8 af[4][2], bfr[2];
  const int NT = K >> 6;

  STG_A(0); STG_B(0); STG_A(1);
  asm volatile("s_waitcnt vmcnt(2)" ::: "memory");  // A(0), B(0) landed
  __builtin_amdgcn_s_barrier();

  for (int t = 0; t < NT; ++t) {
    const char* bufp = ldsc + ((t & 1) << 15);
    // ---- P0: all m x n01 ----
#pragma unroll
    for (int mf = 0; mf < 4; mf++) {
      af[mf][0] = *(const bf16x8*)(bufp + aoff[mf] + colx0);
      af[mf][1] = *(const bf16x8*)(bufp + aoff[mf] + colx1);
    }
    bfr[0] = *(const bf16x8*)(bufp + boff[0] + colx0);
    bfr[1] = *(const bf16x8*)(bufp + boff[0] + colx1);
    if (t + 1 < NT) STG_B(t + 1);
    GATE();
    __builtin_amdgcn_s_setprio(1);
#pragma unroll
    for (int mf = 0; mf < 4; mf++) {
      acc[mf][0] = MFMA_BF16(af[mf][0], bfr[0], acc[mf][0]);
      acc[mf][0] = MFMA_BF16(af[mf][1], bfr[1], acc[mf][0]);
    }
    __builtin_amdgcn_s_setprio(0);
    __builtin_amdgcn_s_barrier();
    // ---- P1: all m x n23 ----
    bfr[0] = *(const bf16x8*)(bufp + boff[1] + colx0);
    bfr[1] = *(const bf16x8*)(bufp + boff[1] + colx1);
    if (t + 2 < NT) STG_A(t + 2);
    GATE();
    __builtin_amdgcn_s_setprio(1);
#pragma unroll
    for (int mf = 0; mf < 4; mf++) {
      acc[mf][1] = MFMA_BF16(af[mf][0], bfr[0], acc[mf][1]);
      acc[mf][1] = MFMA_BF16(af[mf][1], bfr[1], acc[mf][1]);
    }
    __builtin_amdgcn_s_setprio(0);
    if (t + 2 < NT)      { asm volatile("s_waitcnt vmcnt(2)" ::: "memory"); }
    else if (t + 1 < NT) { asm volatile("s_waitcnt vmcnt(0)" ::: "memory"); }
    __builtin_amdgcn_s_barrier();
  }
#undef STG_A
#undef STG_B
#undef GATE

  // epilogue: row = m0+wm*64+mf*16+kgrp*4+r, col = n0+nf*64+wn*16+row16
#pragma unroll
  for (int mf = 0; mf < 4; mf++) {
    const int rowb = m0 + wm * 64 + mf * 16 + kgrp * 4;
#pragma unroll
    for (int nf = 0; nf < 2; nf++) {
      const int col = n0 + nf * 64 + wn * 16 + row16;
#pragma unroll
      for (int r = 0; r < 4; r++) {
        const float v = acc[mf][nf][r];
        const int rr2 = rowb + r;
        if constexpr (EPI == 0) {
          const int bbx = rr2 >> 10, s = rr2 & 1023;
          if (col < 1024) {
            const int hh = col >> 6, d = col & 63;
            qb[(((size_t)(bbx * NH_ + hh)) * S_ + s) * HD_ + d] = (bf16_t)(v * 0.125f);
          } else if (col < 2048) {
            const int c = col - 1024, hh = c >> 6, d = c & 63;
            kb[(((size_t)(bbx * NH_ + hh)) * S_ + s) * HD_ + d] = (bf16_t)v;
          } else {
            const int c = col - 2048, hh = c >> 6, d = c & 63;
            vtb[(((size_t)(bbx * NH_ + hh)) * HD_ + d) * S_ + s] = (bf16_t)v;
          }
        } else if constexpr (EPI == 1) {
          fout[(size_t)rr2 * N + col] += v;
        } else if constexpr (EPI == 2) {
          bout[(size_t)rr2 * N + col] = (bf16_t)fmaxf(v + bias[col], 0.0f);
        } else if constexpr (EPI == 3) {
          fout[(size_t)rr2 * N + col] += v + bias[col];
        } else {
          fout[(size_t)rr2 * N + col] = v + bias[col];
        }
      }
    }
  }
}

// ---------------------------------------------------------------------------
// Flash attention (causal), KVBLK=64, antithetic pairing — EXACT r17 body
// (verified through full timed run). MFMA denominator accL = P @ ones.
// Each block processes qtiles {p, 15-p} = 17 work-units; grid 512.
// ---------------------------------------------------------------------------
__global__ __launch_bounds__(256, 3) void attn_flash(const bf16_t* __restrict__ qg,
                                                     const bf16_t* __restrict__ kg,
                                                     const bf16_t* __restrict__ vtg,
                                                     bf16_t* __restrict__ aout) {
  const int nb = gridDim.x;  // 512
  const int logical = ((blockIdx.x & 7) * (nb >> 3)) + (blockIdx.x >> 3);
  const int pair = logical & 7;   // 0..7
  const int bh   = logical >> 3;  // 0..63
  const int tid = threadIdx.x;
  const int wave = tid >> 6, lane = tid & 63;
  const int row16 = lane & 15, kgrp = lane >> 4;

  const bf16_t* qb = qg + (size_t)bh * S_ * HD_;
  const bf16_t* kb = kg + (size_t)bh * S_ * HD_;
  const bf16_t* vb = vtg + (size_t)bh * HD_ * S_;

  bf16x8 ones;
#pragma unroll
  for (int i = 0; i < 8; i++) ones[i] = (bf16_t)1.0f;

  __shared__ char sP[4][2048];
  char* const sw = &sP[wave][0];
  const int b = bh >> 4, hh = bh & 15;

  for (int it = 0; it < 2; ++it) {
    const int qtile = it ? (15 - pair) : pair;
    const int q0 = qtile * 64 + wave * 16;

    const bf16x8 qf0 = *(const bf16x8*)&qb[(size_t)(q0 + row16) * HD_ + kgrp * 8];
    const bf16x8 qf1 = *(const bf16x8*)&qb[(size_t)(q0 + row16) * HD_ + 32 + kgrp * 8];

    f32x4 accO[4] = {};
    f32x4 accL = {};
    float mrun[4] = {-1e30f, -1e30f, -1e30f, -1e30f};

    const int NTt = qtile + 1;

    bf16x8 kf[4][2];
#pragma unroll
    for (int q = 0; q < 4; q++) {
      kf[q][0] = *(const bf16x8*)&kb[(size_t)(q * 16 + row16) * HD_ + kgrp * 8];
      kf[q][1] = *(const bf16x8*)&kb[(size_t)(q * 16 + row16) * HD_ + 32 + kgrp * 8];
    }

    for (int t = 0; t < NTt; ++t) {
      const int k0 = t * 64;
      f32x4 sc[4];
#pragma unroll
      for (int q = 0; q < 4; q++) {
        f32x4 z = {};
        z = MFMA_BF16(qf0, kf[q][0], z);
        sc[q] = MFMA_BF16(qf1, kf[q][1], z);
      }
      bf16x8 vf[4][2];
#pragma unroll
      for (int d = 0; d < 4; d++) {
        vf[d][0] = *(const bf16x8*)&vb[(size_t)(d * 16 + row16) * S_ + k0 + kgrp * 8];
        vf[d][1] = *(const bf16x8*)&vb[(size_t)(d * 16 + row16) * S_ + k0 + 32 + kgrp * 8];
      }
      const bool diag = (k0 + 64 > q0);
      float p[4][4];
#pragma unroll
      for (int r = 0; r < 4; r++) {
        const int qglob = q0 + kgrp * 4 + r;
        float s0 = sc[0][r], s1 = sc[1][r], s2 = sc[2][r], s3 = sc[3][r];
        if (diag) {
          s0 = (k0 + row16 <= qglob) ? s0 : -1e30f;
          s1 = (k0 + 16 + row16 <= qglob) ? s1 : -1e30f;
          s2 = (k0 + 32 + row16 <= qglob) ? s2 : -1e30f;
          s3 = (k0 + 48 + row16 <= qglob) ? s3 : -1e30f;
        }
        float tmax = fmaxf(fmaxf(s0, s1), fmaxf(s2, s3));
#pragma unroll
        for (int msk = 1; msk < 16; msk <<= 1) tmax = fmaxf(tmax, __shfl_xor(tmax, msk, 64));
        const float mnew  = fmaxf(mrun[r], tmax);
        const float alpha = __expf(mrun[r] - mnew);
        mrun[r] = mnew;
        p[r][0] = __expf(s0 - mnew);
        p[r][1] = __expf(s1 - mnew);
        p[r][2] = __expf(s2 - mnew);
        p[r][3] = __expf(s3 - mnew);
        accL[r] *= alpha;
#pragma unroll
        for (int d = 0; d < 4; d++) accO[d][r] *= alpha;
      }
      if (t + 1 < NTt) {
        const int k0n = k0 + 64;
#pragma unroll
        for (int q = 0; q < 4; q++) {
          kf[q][0] = *(const bf16x8*)&kb[(size_t)(k0n + q * 16 + row16) * HD_ + kgrp * 8];
          kf[q][1] = *(const bf16x8*)&kb[(size_t)(k0n + q * 16 + row16) * HD_ + 32 + kgrp * 8];
        }
      }
#pragma unroll
      for (int r = 0; r < 4; r++) {
        const int prow = kgrp * 4 + r;
        const int px = (prow & 7) << 4;
#pragma unroll
        for (int q = 0; q < 4; q++) {
          *(bf16_t*)(sw + prow * 128 + (((q * 16 + row16) * 2) ^ px)) = (bf16_t)p[r][q];
        }
      }
      const int rx = (row16 & 7) << 4;
      const bf16x8 pf0 = *(const bf16x8*)(sw + row16 * 128 + ((kgrp * 16) ^ rx));
      const bf16x8 pf1 = *(const bf16x8*)(sw + row16 * 128 + ((64 + kgrp * 16) ^ rx));
      accL = MFMA_BF16(pf0, ones, accL);
      accL = MFMA_BF16(pf1, ones, accL);
#pragma unroll
      for (int d = 0; d < 4; d++) {
        accO[d] = MFMA_BF16(pf0, vf[d][0], accO[d]);
        accO[d] = MFMA_BF16(pf1, vf[d][1], accO[d]);
      }
    }

    float rinv[4];
#pragma unroll
    for (int r = 0; r < 4; r++) rinv[r] = 1.0f / accL[r];
#pragma unroll
    for (int d = 0; d < 4; d++)
#pragma unroll
      for (int r = 0; r < 4; r++) {
        const int tok = b * S_ + q0 + kgrp * 4 + r;
        aout[(size_t)tok * D_ + hh * HD_ + d * 16 + row16] = (bf16_t)(accO[d][r] * rinv[r]);
      }
  }
}

// ---------------------------------------------------------------------------
// Launch
// ---------------------------------------------------------------------------
extern "C" void kernel_launch(void* const* d_in, const int* in_sizes, int n_in,
                              void* d_out, int out_size, void* d_ws, size_t ws_size,
                              hipStream_t stream) {
  const int*   x      = (const int*)d_in[0];
  const float* emb_W  = (const float*)d_in[1];
  const float* q_W    = (const float*)d_in[2];
  const float* k_W    = (const float*)d_in[3];
  const float* v_W    = (const float*)d_in[4];
  const float* o_W    = (const float*)d_in[5];
  const float* ln0_g  = (const float*)d_in[6];
  const float* ln0_b  = (const float*)d_in[7];
  const float* ln1_g  = (const float*)d_in[8];
  const float* ln1_b  = (const float*)d_in[9];
  const float* ffn_W1 = (const float*)d_in[10];
  const float* ffn_b1 = (const float*)d_in[11];
  const float* ffn_W2 = (const float*)d_in[12];
  const float* ffn_b2 = (const float*)d_in[13];
  const float* out_W  = (const float*)d_in[14];
  const float* out_b  = (const float*)d_in[15];
  float* out = (float*)d_out;

  char* p = (char*)d_ws;
  auto take = [&](size_t n) { char* r = p; p += (n + 255) & ~(size_t)255; return r; };
  float*  pe    = (float*)take((size_t)S_ * D_ * 4);
  float*  h     = (float*)take((size_t)TOK_ * D_ * 4);
  bf16_t* ain   = (bf16_t*)take((size_t)TOK_ * D_ * 2);
  bf16_t* attno = (bf16_t*)take((size_t)TOK_ * D_ * 2);
  bf16_t* qb    = (bf16_t*)take((size_t)B_ * NH_ * S_ * HD_ * 2);
  bf16_t* kb    = (bf16_t*)take((size_t)B_ * NH_ * S_ * HD_ * 2);
  bf16_t* vtb   = (bf16_t*)take((size_t)B_ * NH_ * S_ * HD_ * 2);
  bf16_t* ff    = (bf16_t*)take((size_t)TOK_ * HF_ * 2);
  bf16_t* qkvW  = (bf16_t*)take((size_t)3 * D_ * D_ * 2);
  bf16_t* oWb   = (bf16_t*)take((size_t)D_ * D_ * 2);
  bf16_t* W1b   = (bf16_t*)take((size_t)HF_ * D_ * 2);
  bf16_t* W2b   = (bf16_t*)take((size_t)D_ * HF_ * 2);
  bf16_t* outWb = (bf16_t*)take((size_t)V_ * D_ * 2);

  // --- weights -> bf16 ---
  cvt_f32_bf16<<<1024, 256, 0, stream>>>(q_W, qkvW, D_ * D_ / 4);
  cvt_f32_bf16<<<1024, 256, 0, stream>>>(k_W, qkvW + (size_t)D_ * D_, D_ * D_ / 4);
  cvt_f32_bf16<<<1024, 256, 0, stream>>>(v_W, qkvW + (size_t)2 * D_ * D_, D_ * D_ / 4);
  cvt_f32_bf16<<<1024, 256, 0, stream>>>(o_W, oWb, D_ * D_ / 4);
  cvt_f32_bf16<<<4096, 256, 0, stream>>>(ffn_W1, W1b, HF_ * D_ / 4);
  cvt_f32_bf16<<<4096, 256, 0, stream>>>(ffn_W2, W2b, D_ * HF_ / 4);
  cvt_f32_bf16<<<32000, 256, 0, stream>>>(out_W, outWb, V_ * D_ / 4);

  // --- embedding + PE ---
  pe_kernel<<<S_, 256, 0, stream>>>(pe);
  embed_kernel<<<TOK_ * D_ / 4 / 256, 256, 0, stream>>>(x, emb_W, pe, h);

  // --- transformer blocks (shared weights) ---
  for (int blk = 0; blk < 4; blk++) {
    ln_res_kernel<<<TOK_, 256, 0, stream>>>(h, ln0_g, ln0_b, ain);
    gemm_sq<0><<<32 * (3 * D_ / 128), 512, 0, stream>>>(
        ain, qkvW, 3 * D_, D_, 8, 8, nullptr, nullptr, nullptr, qb, kb, vtb);
    attn_flash<<<8 * B_ * NH_, 256, 0, stream>>>(qb, kb, vtb, attno);
    gemm_sq<1><<<32 * (D_ / 128), 512, 0, stream>>>(
        attno, oWb, D_, D_, 8, 8, h, nullptr, nullptr, nullptr, nullptr, nullptr);
    ln_res_kernel<<<TOK_, 256, 0, stream>>>(h, ln1_g, ln1_b, ain);
    gemm_sq<2><<<32 * (HF_ / 128), 512, 0, stream>>>(
        ain, W1b, HF_, D_, 8, 8, nullptr, ffn_b1, ff, nullptr, nullptr, nullptr);
    gemm_sq<3><<<32 * (D_ / 128), 512, 0, stream>>>(
        ff, W2b, D_, HF_, D_ / 128, 32, h, ffn_b2, nullptr, nullptr, nullptr, nullptr);
  }

  // --- final logits: supertile {10 N-tiles} x {4 M-tiles} (verified r13) ---
  cvt_f32_bf16<<<4096, 256, 0, stream>>>(h, ain, TOK_ * D_ / 4);
  gemm_sq<4><<<32 * (V_ / 128), 512, 0, stream>>>(
      ain, outWb, V_, D_, 10, 4, out, out_b, nullptr, nullptr, nullptr, nullptr);
}

// Round 21
// 1349.404 us; speedup vs baseline: 1.1756x; 1.0230x over previous
//
#include <hip/hip_runtime.h>
#include <hip/hip_bf16.h>
#include <math.h>

// ---------------------------------------------------------------------------
// Types
// ---------------------------------------------------------------------------
typedef __bf16 bf16_t;
typedef __bf16 bf16x8 __attribute__((ext_vector_type(8)));
typedef __bf16 bf16x4 __attribute__((ext_vector_type(4)));
typedef float  f32x4  __attribute__((ext_vector_type(4)));

#define MFMA_BF16(a, b, c) __builtin_amdgcn_mfma_f32_16x16x32_bf16((a), (b), (c), 0, 0, 0)

typedef const void __attribute__((address_space(1)))* gas_ptr;
typedef void       __attribute__((address_space(3)))* las_ptr;

__device__ __forceinline__ void gload_lds16(const void* g, void* l) {
  // global -> LDS direct, 16B per lane. LDS dest is wave-uniform base + lane*16.
  __builtin_amdgcn_global_load_lds((gas_ptr)g, (las_ptr)l, 16, 0, 0);
}

// ---------------------------------------------------------------------------
// Model constants
// ---------------------------------------------------------------------------
static constexpr int B_ = 4, S_ = 1024, D_ = 1024, HF_ = 4096, V_ = 32000;
static constexpr int NH_ = 16, HD_ = 64;
static constexpr int TOK_ = B_ * S_;  // 4096

// ---------------------------------------------------------------------------
// fp32 -> bf16 conversion (vectorized x4)
// ---------------------------------------------------------------------------
__global__ __launch_bounds__(256) void cvt_f32_bf16(const float* __restrict__ in,
                                                    bf16_t* __restrict__ out, int n4) {
  int i = blockIdx.x * 256 + threadIdx.x;
  if (i < n4) {
    float4 v = ((const float4*)in)[i];
    bf16x4 o;
    o[0] = (bf16_t)v.x; o[1] = (bf16_t)v.y; o[2] = (bf16_t)v.z; o[3] = (bf16_t)v.w;
    ((bf16x4*)out)[i] = o;
  }
}

// ---------------------------------------------------------------------------
// Sinusoidal positional encoding table
// ---------------------------------------------------------------------------
__global__ __launch_bounds__(256) void pe_kernel(float* __restrict__ pe) {
  const int s = blockIdx.x;
  for (int i = threadIdx.x; i < D_ / 2; i += 256) {
    float div = expf((2.0f * (float)i) * (-9.210340371976184f / (float)D_)); // ln(10000)
    float a = (float)s * div;
    pe[(size_t)s * D_ + 2 * i]     = sinf(a);
    pe[(size_t)s * D_ + 2 * i + 1] = cosf(a);
  }
}

// ---------------------------------------------------------------------------
// Embedding: h[t][d] = emb_W[x[t]][d] * 32 + pe[t % S][d]
// ---------------------------------------------------------------------------
__global__ __launch_bounds__(256) void embed_kernel(const int* __restrict__ x,
                                                    const float* __restrict__ embW,
                                                    const float* __restrict__ pe,
                                                    float* __restrict__ h) {
  int i = blockIdx.x * 256 + threadIdx.x;
  int token = i >> 8;
  int c4 = i & 255;
  int idx = x[token];
  float4 e = ((const float4*)(embW + (size_t)idx * D_))[c4];
  float4 p = ((const float4*)(pe + (size_t)(token & (S_ - 1)) * D_))[c4];
  float4 o;
  o.x = e.x * 32.0f + p.x; o.y = e.y * 32.0f + p.y;
  o.z = e.z * 32.0f + p.z; o.w = e.w * 32.0f + p.w;
  ((float4*)(h + (size_t)token * D_))[c4] = o;
}

// ---------------------------------------------------------------------------
// a_in = h + LayerNorm(h)*g + b   -> bf16
// ---------------------------------------------------------------------------
__global__ __launch_bounds__(256) void ln_res_kernel(const float* __restrict__ h,
                                                     const float* __restrict__ gamma,
                                                     const float* __restrict__ beta,
                                                     bf16_t* __restrict__ out) {
  const int row = blockIdx.x;
  const int tid = threadIdx.x;
  const float4 v = ((const float4*)(h + (size_t)row * D_))[tid];
  float s  = v.x + v.y + v.z + v.w;
  float s2 = v.x * v.x + v.y * v.y + v.z * v.z + v.w * v.w;
#pragma unroll
  for (int m = 1; m < 64; m <<= 1) {
    s  += __shfl_xor(s, m, 64);
    s2 += __shfl_xor(s2, m, 64);
  }
  __shared__ float red[2][4];
  const int wave = tid >> 6, lane = tid & 63;
  if (lane == 0) { red[0][wave] = s; red[1][wave] = s2; }
  __syncthreads();
  s  = red[0][0] + red[0][1] + red[0][2] + red[0][3];
  s2 = red[1][0] + red[1][1] + red[1][2] + red[1][3];
  const float mu   = s * (1.0f / D_);
  const float rstd = rsqrtf(s2 * (1.0f / D_) - mu * mu + 1e-5f);
  const float4 g4 = ((const float4*)gamma)[tid];
  const float4 b4 = ((const float4*)beta)[tid];
  bf16x4 o;
  o[0] = (bf16_t)(v.x + (v.x - mu) * rstd * g4.x + b4.x);
  o[1] = (bf16_t)(v.y + (v.y - mu) * rstd * g4.y + b4.y);
  o[2] = (bf16_t)(v.z + (v.z - mu) * rstd * g4.z + b4.z);
  o[3] = (bf16_t)(v.w + (v.w - mu) * rstd * g4.w + b4.w);
  ((bf16x4*)(out + (size_t)row * D_))[tid] = o;
}

// ---------------------------------------------------------------------------
// gemm_sq: 128x128 tile, BK=64, 2 phases/K-tile, 2 blocks/CU (verified r10).
// C[4096,N] = A[4096,K] @ W[N,K]^T. 8 waves (2M x 4N); per-wave 64x32.
// LDS 2 x 32 KB dbuf; launch_bounds(512,4) => 2 blocks/CU; sibling block
// covers barrier/drain/epilogue stalls. Counted vmcnt(2), never 0 mid-loop.
// Swizzle: 128B rows, byte ^ ((row&7)<<4), involution. XCD swizzle +
// 2-D SUPERTILE ordering (verified r13/r16). Sizing rule: live set =
// mch*256KB (A) + band_n*256KB (B) <= 4MB with band_n*mch ~= 64.
//   logits: (10,4); QKV/FFN1/O-proj: (8,8); FFN2: identity (A L3-resident).
// Epilogues: 0 QKV-scatter, 1 fout+=v, 2 relu(v+bias)->bf16, 3 fout+=v+bias,
//            4 fout = v + bias via LDS-staged coalesced NONTEMPORAL f32x4
//              stores (r20: keeps A/B L3-resident under the 512MB C stream).
// ---------------------------------------------------------------------------
template <int EPI>
__global__ __launch_bounds__(512, 4) void gemm_sq(
    const bf16_t* __restrict__ A, const bf16_t* __restrict__ W, int N, int K,
    int band_n, int mch,
    float* __restrict__ fout, const float* __restrict__ bias, bf16_t* __restrict__ bout,
    bf16_t* __restrict__ qb, bf16_t* __restrict__ kb, bf16_t* __restrict__ vtb) {
  __shared__ char lds[2][32768];

  const int tid = threadIdx.x;
  const int wave = tid >> 6, lane = tid & 63;
  const int row16 = lane & 15, kgrp = lane >> 4;
  const int wm = wave >> 2, wn = wave & 3;  // 2M x 4N

  const int nb = gridDim.x;  // multiple of 8
  const int logical = (blockIdx.x & 7) * (nb >> 3) + (blockIdx.x >> 3);
  // supertile decode: {band of band_n N-tiles} x {chunk of mch M-tiles},
  // M fastest within supertile; chunks inner, bands outer. (M = 32 tiles)
  const int st = band_n * mch;
  const int stid = logical / st;
  const int rr = logical - stid * st;
  const int nMch = 32 / mch;
  const int band = stid / nMch;
  const int mchid = stid - band * nMch;
  const int m0 = (mchid * mch + (rr % mch)) << 7;
  const int n0 = (band * band_n + rr / mch) << 7;
  const size_t K2 = (size_t)K * 2;

  const int lr = lane >> 3;
  const int swz = ((lane & 7) * 16) ^ (lr << 4);
  const char* gA = (const char*)A + (size_t)(m0 + wave * 8 + lr) * K2 + swz;
  const char* gB = (const char*)W + (size_t)(n0 + wave * 8 + lr) * K2 + swz;
  char* const ldsc = &lds[0][0];
  const int dW = wave * 1024;

#define STG_A(v)                                                  \
  { char* d_ = ldsc + (((v) & 1) << 15) + dW;                     \
    const char* g_ = gA + (size_t)(v) * 128;                      \
    gload_lds16(g_, d_); gload_lds16(g_ + 64 * K2, d_ + 8192); }
#define STG_B(v)                                                  \
  { char* d_ = ldsc + (((v) & 1) << 15) + 16384 + dW;             \
    const char* g_ = gB + (size_t)(v) * 128;                      \
    gload_lds16(g_, d_); gload_lds16(g_ + 64 * K2, d_ + 8192); }

  const int colx0 = (kgrp * 16) ^ ((row16 & 7) << 4);
  const int colx1 = (64 + kgrp * 16) ^ ((row16 & 7) << 4);
  int aoff[4], boff[2];
#pragma unroll
  for (int mf = 0; mf < 4; mf++) aoff[mf] = (wm * 64 + mf * 16 + row16) * 128;
#pragma unroll
  for (int nf = 0; nf < 2; nf++) boff[nf] = 16384 + (nf * 64 + wn * 16 + row16) * 128;

#define GATE()                                        \
  __builtin_amdgcn_s_barrier();                       \
  asm volatile("s_waitcnt lgkmcnt(0)" ::: "memory");  \
  __builtin_amdgcn_sched_barrier(0);

  f32x4 acc[4][2] = {};
  bf16x8 af[4][2], bfr[2];
  const int NT = K >> 6;

  STG_A(0); STG_B(0); STG_A(1);
  asm volatile("s_waitcnt vmcnt(2)" ::: "memory");  // A(0), B(0) landed
  __builtin_amdgcn_s_barrier();

  for (int t = 0; t < NT; ++t) {
    const char* bufp = ldsc + ((t & 1) << 15);
    // ---- P0: all m x n01 ----
#pragma unroll
    for (int mf = 0; mf < 4; mf++) {
      af[mf][0] = *(const bf16x8*)(bufp + aoff[mf] + colx0);
      af[mf][1] = *(const bf16x8*)(bufp + aoff[mf] + colx1);
    }
    bfr[0] = *(const bf16x8*)(bufp + boff[0] + colx0);
    bfr[1] = *(const bf16x8*)(bufp + boff[0] + colx1);
    if (t + 1 < NT) STG_B(t + 1);
    GATE();
    __builtin_amdgcn_s_setprio(1);
#pragma unroll
    for (int mf = 0; mf < 4; mf++) {
      acc[mf][0] = MFMA_BF16(af[mf][0], bfr[0], acc[mf][0]);
      acc[mf][0] = MFMA_BF16(af[mf][1], bfr[1], acc[mf][0]);
    }
    __builtin_amdgcn_s_setprio(0);
    __builtin_amdgcn_s_barrier();
    // ---- P1: all m x n23 ----
    bfr[0] = *(const bf16x8*)(bufp + boff[1] + colx0);
    bfr[1] = *(const bf16x8*)(bufp + boff[1] + colx1);
    if (t + 2 < NT) STG_A(t + 2);
    GATE();
    __builtin_amdgcn_s_setprio(1);
#pragma unroll
    for (int mf = 0; mf < 4; mf++) {
      acc[mf][1] = MFMA_BF16(af[mf][0], bfr[0], acc[mf][1]);
      acc[mf][1] = MFMA_BF16(af[mf][1], bfr[1], acc[mf][1]);
    }
    __builtin_amdgcn_s_setprio(0);
    if (t + 2 < NT)      { asm volatile("s_waitcnt vmcnt(2)" ::: "memory"); }
    else if (t + 1 < NT) { asm volatile("s_waitcnt vmcnt(0)" ::: "memory"); }
    __builtin_amdgcn_s_barrier();
  }
#undef STG_A
#undef STG_B
#undef GATE

  if constexpr (EPI == 4) {
    // LDS-staged coalesced nontemporal epilogue: acc(+bias) -> LDS [128][128]
    // f32 tile (main loop done; 64 KB LDS free), then stream 512B row-runs of
    // f32x4 nt stores (perfect 128B transactions, no write amplification).
    float* lf = (float*)ldsc;
#pragma unroll
    for (int mf = 0; mf < 4; mf++) {
      const int rowl = wm * 64 + mf * 16 + kgrp * 4;
#pragma unroll
      for (int nf = 0; nf < 2; nf++) {
        const int coll = nf * 64 + wn * 16 + row16;
        const float bv = bias[n0 + coll];
#pragma unroll
        for (int r = 0; r < 4; r++) lf[(rowl + r) * 128 + coll] = acc[mf][nf][r] + bv;
      }
    }
    __syncthreads();
    const int rowR = tid >> 5;   // 0..15
    const int cR   = tid & 31;   // f32x4 chunk within row
#pragma unroll
    for (int pass = 0; pass < 8; ++pass) {
      const int rrow = pass * 16 + rowR;
      const f32x4 v = *(const f32x4*)(lf + rrow * 128 + cR * 4);
      __builtin_nontemporal_store(
          v, (f32x4*)&fout[(size_t)(m0 + rrow) * N + n0 + cR * 4]);
    }
  } else {
    // epilogue: row = m0+wm*64+mf*16+kgrp*4+r, col = n0+nf*64+wn*16+row16
#pragma unroll
    for (int mf = 0; mf < 4; mf++) {
      const int rowb = m0 + wm * 64 + mf * 16 + kgrp * 4;
#pragma unroll
      for (int nf = 0; nf < 2; nf++) {
        const int col = n0 + nf * 64 + wn * 16 + row16;
#pragma unroll
        for (int r = 0; r < 4; r++) {
          const float v = acc[mf][nf][r];
          const int rr2 = rowb + r;
          if constexpr (EPI == 0) {
            const int bbx = rr2 >> 10, s = rr2 & 1023;
            if (col < 1024) {
              const int hh = col >> 6, d = col & 63;
              qb[(((size_t)(bbx * NH_ + hh)) * S_ + s) * HD_ + d] = (bf16_t)(v * 0.125f);
            } else if (col < 2048) {
              const int c = col - 1024, hh = c >> 6, d = c & 63;
              kb[(((size_t)(bbx * NH_ + hh)) * S_ + s) * HD_ + d] = (bf16_t)v;
            } else {
              const int c = col - 2048, hh = c >> 6, d = c & 63;
              vtb[(((size_t)(bbx * NH_ + hh)) * HD_ + d) * S_ + s] = (bf16_t)v;
            }
          } else if constexpr (EPI == 1) {
            fout[(size_t)rr2 * N + col] += v;
          } else if constexpr (EPI == 2) {
            bout[(size_t)rr2 * N + col] = (bf16_t)fmaxf(v + bias[col], 0.0f);
          } else {
            fout[(size_t)rr2 * N + col] += v + bias[col];
          }
        }
      }
    }
  }
}

// ---------------------------------------------------------------------------
// Flash attention (causal), KVBLK=64, antithetic pairing — EXACT r17 body
// (verified through full timed run). MFMA denominator accL = P @ ones.
// Each block processes qtiles {p, 15-p} = 17 work-units; grid 512.
// ---------------------------------------------------------------------------
__global__ __launch_bounds__(256, 3) void attn_flash(const bf16_t* __restrict__ qg,
                                                     const bf16_t* __restrict__ kg,
                                                     const bf16_t* __restrict__ vtg,
                                                     bf16_t* __restrict__ aout) {
  const int nb = gridDim.x;  // 512
  const int logical = ((blockIdx.x & 7) * (nb >> 3)) + (blockIdx.x >> 3);
  const int pair = logical & 7;   // 0..7
  const int bh   = logical >> 3;  // 0..63
  const int tid = threadIdx.x;
  const int wave = tid >> 6, lane = tid & 63;
  const int row16 = lane & 15, kgrp = lane >> 4;

  const bf16_t* qb = qg + (size_t)bh * S_ * HD_;
  const bf16_t* kb = kg + (size_t)bh * S_ * HD_;
  const bf16_t* vb = vtg + (size_t)bh * HD_ * S_;

  bf16x8 ones;
#pragma unroll
  for (int i = 0; i < 8; i++) ones[i] = (bf16_t)1.0f;

  __shared__ char sP[4][2048];
  char* const sw = &sP[wave][0];
  const int b = bh >> 4, hh = bh & 15;

  for (int it = 0; it < 2; ++it) {
    const int qtile = it ? (15 - pair) : pair;
    const int q0 = qtile * 64 + wave * 16;

    const bf16x8 qf0 = *(const bf16x8*)&qb[(size_t)(q0 + row16) * HD_ + kgrp * 8];
    const bf16x8 qf1 = *(const bf16x8*)&qb[(size_t)(q0 + row16) * HD_ + 32 + kgrp * 8];

    f32x4 accO[4] = {};
    f32x4 accL = {};
    float mrun[4] = {-1e30f, -1e30f, -1e30f, -1e30f};

    const int NTt = qtile + 1;

    bf16x8 kf[4][2];
#pragma unroll
    for (int q = 0; q < 4; q++) {
      kf[q][0] = *(const bf16x8*)&kb[(size_t)(q * 16 + row16) * HD_ + kgrp * 8];
      kf[q][1] = *(const bf16x8*)&kb[(size_t)(q * 16 + row16) * HD_ + 32 + kgrp * 8];
    }

    for (int t = 0; t < NTt; ++t) {
      const int k0 = t * 64;
      f32x4 sc[4];
#pragma unroll
      for (int q = 0; q < 4; q++) {
        f32x4 z = {};
        z = MFMA_BF16(qf0, kf[q][0], z);
        sc[q] = MFMA_BF16(qf1, kf[q][1], z);
      }
      bf16x8 vf[4][2];
#pragma unroll
      for (int d = 0; d < 4; d++) {
        vf[d][0] = *(const bf16x8*)&vb[(size_t)(d * 16 + row16) * S_ + k0 + kgrp * 8];
        vf[d][1] = *(const bf16x8*)&vb[(size_t)(d * 16 + row16) * S_ + k0 + 32 + kgrp * 8];
      }
      const bool diag = (k0 + 64 > q0);
      float p[4][4];
#pragma unroll
      for (int r = 0; r < 4; r++) {
        const int qglob = q0 + kgrp * 4 + r;
        float s0 = sc[0][r], s1 = sc[1][r], s2 = sc[2][r], s3 = sc[3][r];
        if (diag) {
          s0 = (k0 + row16 <= qglob) ? s0 : -1e30f;
          s1 = (k0 + 16 + row16 <= qglob) ? s1 : -1e30f;
          s2 = (k0 + 32 + row16 <= qglob) ? s2 : -1e30f;
          s3 = (k0 + 48 + row16 <= qglob) ? s3 : -1e30f;
        }
        float tmax = fmaxf(fmaxf(s0, s1), fmaxf(s2, s3));
#pragma unroll
        for (int msk = 1; msk < 16; msk <<= 1) tmax = fmaxf(tmax, __shfl_xor(tmax, msk, 64));
        const float mnew  = fmaxf(mrun[r], tmax);
        const float alpha = __expf(mrun[r] - mnew);
        mrun[r] = mnew;
        p[r][0] = __expf(s0 - mnew);
        p[r][1] = __expf(s1 - mnew);
        p[r][2] = __expf(s2 - mnew);
        p[r][3] = __expf(s3 - mnew);
        accL[r] *= alpha;
#pragma unroll
        for (int d = 0; d < 4; d++) accO[d][r] *= alpha;
      }
      if (t + 1 < NTt) {
        const int k0n = k0 + 64;
#pragma unroll
        for (int q = 0; q < 4; q++) {
          kf[q][0] = *(const bf16x8*)&kb[(size_t)(k0n + q * 16 + row16) * HD_ + kgrp * 8];
          kf[q][1] = *(const bf16x8*)&kb[(size_t)(k0n + q * 16 + row16) * HD_ + 32 + kgrp * 8];
        }
      }
#pragma unroll
      for (int r = 0; r < 4; r++) {
        const int prow = kgrp * 4 + r;
        const int px = (prow & 7) << 4;
#pragma unroll
        for (int q = 0; q < 4; q++) {
          *(bf16_t*)(sw + prow * 128 + (((q * 16 + row16) * 2) ^ px)) = (bf16_t)p[r][q];
        }
      }
      const int rx = (row16 & 7) << 4;
      const bf16x8 pf0 = *(const bf16x8*)(sw + row16 * 128 + ((kgrp * 16) ^ rx));
      const bf16x8 pf1 = *(const bf16x8*)(sw + row16 * 128 + ((64 + kgrp * 16) ^ rx));
      accL = MFMA_BF16(pf0, ones, accL);
      accL = MFMA_BF16(pf1, ones, accL);
#pragma unroll
      for (int d = 0; d < 4; d++) {
        accO[d] = MFMA_BF16(pf0, vf[d][0], accO[d]);
        accO[d] = MFMA_BF16(pf1, vf[d][1], accO[d]);
      }
    }

    float rinv[4];
#pragma unroll
    for (int r = 0; r < 4; r++) rinv[r] = 1.0f / accL[r];
#pragma unroll
    for (int d = 0; d < 4; d++)
#pragma unroll
      for (int r = 0; r < 4; r++) {
        const int tok = b * S_ + q0 + kgrp * 4 + r;
        aout[(size_t)tok * D_ + hh * HD_ + d * 16 + row16] = (bf16_t)(accO[d][r] * rinv[r]);
      }
  }
}

// ---------------------------------------------------------------------------
// Launch
// ---------------------------------------------------------------------------
extern "C" void kernel_launch(void* const* d_in, const int* in_sizes, int n_in,
                              void* d_out, int out_size, void* d_ws, size_t ws_size,
                              hipStream_t stream) {
  const int*   x      = (const int*)d_in[0];
  const float* emb_W  = (const float*)d_in[1];
  const float* q_W    = (const float*)d_in[2];
  const float* k_W    = (const float*)d_in[3];
  const float* v_W    = (const float*)d_in[4];
  const float* o_W    = (const float*)d_in[5];
  const float* ln0_g  = (const float*)d_in[6];
  const float* ln0_b  = (const float*)d_in[7];
  const float* ln1_g  = (const float*)d_in[8];
  const float* ln1_b  = (const float*)d_in[9];
  const float* ffn_W1 = (const float*)d_in[10];
  const float* ffn_b1 = (const float*)d_in[11];
  const float* ffn_W2 = (const float*)d_in[12];
  const float* ffn_b2 = (const float*)d_in[13];
  const float* out_W  = (const float*)d_in[14];
  const float* out_b  = (const float*)d_in[15];
  float* out = (float*)d_out;

  char* p = (char*)d_ws;
  auto take = [&](size_t n) { char* r = p; p += (n + 255) & ~(size_t)255; return r; };
  float*  pe    = (float*)take((size_t)S_ * D_ * 4);
  float*  h     = (float*)take((size_t)TOK_ * D_ * 4);
  bf16_t* ain   = (bf16_t*)take((size_t)TOK_ * D_ * 2);
  bf16_t* attno = (bf16_t*)take((size_t)TOK_ * D_ * 2);
  bf16_t* qb    = (bf16_t*)take((size_t)B_ * NH_ * S_ * HD_ * 2);
  bf16_t* kb    = (bf16_t*)take((size_t)B_ * NH_ * S_ * HD_ * 2);
  bf16_t* vtb   = (bf16_t*)take((size_t)B_ * NH_ * S_ * HD_ * 2);
  bf16_t* ff    = (bf16_t*)take((size_t)TOK_ * HF_ * 2);
  bf16_t* qkvW  = (bf16_t*)take((size_t)3 * D_ * D_ * 2);
  bf16_t* oWb   = (bf16_t*)take((size_t)D_ * D_ * 2);
  bf16_t* W1b   = (bf16_t*)take((size_t)HF_ * D_ * 2);
  bf16_t* W2b   = (bf16_t*)take((size_t)D_ * HF_ * 2);
  bf16_t* outWb = (bf16_t*)take((size_t)V_ * D_ * 2);

  // --- weights -> bf16 ---
  cvt_f32_bf16<<<1024, 256, 0, stream>>>(q_W, qkvW, D_ * D_ / 4);
  cvt_f32_bf16<<<1024, 256, 0, stream>>>(k_W, qkvW + (size_t)D_ * D_, D_ * D_ / 4);
  cvt_f32_bf16<<<1024, 256, 0, stream>>>(v_W, qkvW + (size_t)2 * D_ * D_, D_ * D_ / 4);
  cvt_f32_bf16<<<1024, 256, 0, stream>>>(o_W, oWb, D_ * D_ / 4);
  cvt_f32_bf16<<<4096, 256, 0, stream>>>(ffn_W1, W1b, HF_ * D_ / 4);
  cvt_f32_bf16<<<4096, 256, 0, stream>>>(ffn_W2, W2b, D_ * HF_ / 4);
  cvt_f32_bf16<<<32000, 256, 0, stream>>>(out_W, outWb, V_ * D_ / 4);

  // --- embedding + PE ---
  pe_kernel<<<S_, 256, 0, stream>>>(pe);
  embed_kernel<<<TOK_ * D_ / 4 / 256, 256, 0, stream>>>(x, emb_W, pe, h);

  // --- transformer blocks (shared weights) ---
  for (int blk = 0; blk < 4; blk++) {
    ln_res_kernel<<<TOK_, 256, 0, stream>>>(h, ln0_g, ln0_b, ain);
    gemm_sq<0><<<32 * (3 * D_ / 128), 512, 0, stream>>>(
        ain, qkvW, 3 * D_, D_, 8, 8, nullptr, nullptr, nullptr, qb, kb, vtb);
    attn_flash<<<8 * B_ * NH_, 256, 0, stream>>>(qb, kb, vtb, attno);
    gemm_sq<1><<<32 * (D_ / 128), 512, 0, stream>>>(
        attno, oWb, D_, D_, 8, 8, h, nullptr, nullptr, nullptr, nullptr, nullptr);
    ln_res_kernel<<<TOK_, 256, 0, stream>>>(h, ln1_g, ln1_b, ain);
    gemm_sq<2><<<32 * (HF_ / 128), 512, 0, stream>>>(
        ain, W1b, HF_, D_, 8, 8, nullptr, ffn_b1, ff, nullptr, nullptr, nullptr);
    gemm_sq<3><<<32 * (D_ / 128), 512, 0, stream>>>(
        ff, W2b, D_, HF_, D_ / 128, 32, h, ffn_b2, nullptr, nullptr, nullptr, nullptr);
  }

  // --- final logits: supertile {10 N-tiles} x {4 M-tiles} + nt epilogue ---
  cvt_f32_bf16<<<4096, 256, 0, stream>>>(h, ain, TOK_ * D_ / 4);
  gemm_sq<4><<<32 * (V_ / 128), 512, 0, stream>>>(
      ain, outWb, V_, D_, 10, 4, out, out_b, nullptr, nullptr, nullptr, nullptr);
}